// Round 11
// baseline (269.414 us; speedup 1.0000x reference)
//
#include <hip/hip_runtime.h>
#include <hip/hip_fp16.h>

#define NT      250000
#define NN      20000
#define RP      8
#define EMB     64
#define NCLS    16
#define NRELS   64
#define KMAX    140000    // max segment id + 1 (19999*7 = 139993)

// ---------------- A: LDS-row-tiled per-thread GEMV + softmax ----------------
// l1 written in CSC order via cscpos (scattered writes = no latency stall);
// l2 stays p-order (consumed contiguously by k_h / k_l2out).
__global__ __launch_bounds__(256) void k_gemv(
    const float* __restrict__ rm,
    const float* __restrict__ W1, const float* __restrict__ b1,
    const float* __restrict__ W2, const float* __restrict__ b2,
    const int* __restrict__ cscpos,
    float* __restrict__ l1csc, float* __restrict__ l2)
{
    __shared__ float tile[256 * 20];
    int t = threadIdx.x;
    int base = blockIdx.x * 256;
    float a1[8], a2[8];
#pragma unroll
    for (int r = 0; r < 8; ++r) { a1[r] = b1[r]; a2[r] = b2[r]; }

#pragma unroll 1
    for (int kc = 0; kc < 4; ++kc) {
        __syncthreads();
#pragma unroll
        for (int q = 0; q < 4; ++q) {
            int i = q * 256 + t;
            int pl = i >> 2, j4 = i & 3;
            int p = base + pl;
            float4 v = make_float4(0.f, 0.f, 0.f, 0.f);
            if (p < NT) v = reinterpret_cast<const float4*>(rm)[(size_t)p * 16 + kc * 4 + j4];
            *reinterpret_cast<float4*>(&tile[pl * 20 + j4 * 4]) = v;
        }
        __syncthreads();
        float xr[16];
#pragma unroll
        for (int j4 = 0; j4 < 4; ++j4) {
            float4 v = *reinterpret_cast<const float4*>(&tile[t * 20 + j4 * 4]);
            xr[j4 * 4 + 0] = v.x; xr[j4 * 4 + 1] = v.y;
            xr[j4 * 4 + 2] = v.z; xr[j4 * 4 + 3] = v.w;
        }
#pragma unroll
        for (int kk = 0; kk < 16; ++kk) {
            float x = xr[kk];
            int k = kc * 16 + kk;
#pragma unroll
            for (int r = 0; r < 8; ++r) {
                a1[r] = fmaf(x, W1[k * 8 + r], a1[r]);
                a2[r] = fmaf(x, W2[k * 8 + r], a2[r]);
            }
        }
    }
    int p = base + t;
    if (p >= NT) return;
    float mx = a2[0];
#pragma unroll
    for (int r = 1; r < 8; ++r) mx = fmaxf(mx, a2[r]);
    float sm = 0.f;
#pragma unroll
    for (int r = 0; r < 8; ++r) { a2[r] = __expf(a2[r] - mx); sm += a2[r]; }
    float inv = 1.0f / sm;
#pragma unroll
    for (int r = 0; r < 8; ++r) a2[r] *= inv;
    int q = cscpos[p];
    float4* o1 = reinterpret_cast<float4*>(l1csc + (size_t)q * 8);
    float4* o2 = reinterpret_cast<float4*>(l2 + (size_t)p * 8);
    o1[0] = make_float4(a1[0], a1[1], a1[2], a1[3]);
    o1[1] = make_float4(a1[4], a1[5], a1[6], a1[7]);
    o2[0] = make_float4(a2[0], a2[1], a2[2], a2[3]);
    o2[1] = make_float4(a2[4], a2[5], a2[6], a2[7]);
}

// ---------------- CSR offsets (hrow sorted by np.unique) ----------------
__global__ __launch_bounds__(256) void k_rowptr(
    const int* __restrict__ hrow, int* __restrict__ rowptr)
{
    int i = blockIdx.x * blockDim.x + threadIdx.x;
    if (i > NN) return;
    int lo = 0, hi = NT;
    while (lo < hi) { int mid = (lo + hi) >> 1; if (hrow[mid] < i) lo = mid + 1; else hi = mid; }
    rowptr[i] = lo;
}

// ---------------- CSC build ----------------
__global__ __launch_bounds__(256) void k_hist(
    const int* __restrict__ vcol, int* __restrict__ cnt)
{
    int p = blockIdx.x * blockDim.x + threadIdx.x;
    if (p < NT) atomicAdd(&cnt[vcol[p]], 1);
}

__global__ __launch_bounds__(1024) void k_scan(
    const int* __restrict__ cnt, int* __restrict__ cstart, int* __restrict__ cnt2)
{
    __shared__ int part[1024];
    int t = threadIdx.x;
    int base = t * 20;
    int local[20];
    int s = 0;
#pragma unroll
    for (int i = 0; i < 20; ++i) {
        int idx = base + i;
        int c = (idx < NN) ? cnt[idx] : 0;
        local[i] = s;
        s += c;
    }
    part[t] = s;
    __syncthreads();
    for (int off = 1; off < 1024; off <<= 1) {
        int v = (t >= off) ? part[t - off] : 0;
        __syncthreads();
        part[t] += v;
        __syncthreads();
    }
    int ebase = t ? part[t - 1] : 0;
#pragma unroll
    for (int i = 0; i < 20; ++i) {
        int idx = base + i;
        if (idx < NN) { cstart[idx] = ebase + local[i]; cnt2[idx] = ebase + local[i]; }
    }
    if (t == 1023) cstart[NN] = part[1023];
}

__global__ __launch_bounds__(256) void k_pos(
    const int* __restrict__ vcol, int* __restrict__ cnt2,
    int* __restrict__ cscidx, int* __restrict__ cscpos)
{
    int p = blockIdx.x * blockDim.x + threadIdx.x;
    if (p >= NT) return;
    int o = vcol[p];
    int slot = atomicAdd(&cnt2[o], 1);
    cscidx[slot] = p;
    cscpos[p] = slot;
}

// ---------------- colsum: wave per o, coalesced l1csc stream, shfl-reduce ----------------
// lane = j*8 + r; 8 pairs x 8 r per iteration = 256B contiguous reads.
__global__ __launch_bounds__(256) void k_colsum(
    const float* __restrict__ l1csc, const int* __restrict__ cstart,
    float* __restrict__ colsum, float* __restrict__ cs0part)
{
    int o = (int)((blockIdx.x * blockDim.x + threadIdx.x) >> 6);
    int lane = threadIdx.x & 63;
    if (o >= NN) return;
    int qb = cstart[o], qe = cstart[o + 1];
    if (qb == qe) { if (lane == 0) cs0part[o] = 0.f; return; }
    int j = lane >> 3, r = lane & 7;
    float sum = 0.f;
    for (int q0 = qb; q0 < qe; q0 += 8) {
        int q = q0 + j;
        if (q < qe) sum += l1csc[(size_t)q * 8 + r];
    }
    sum += __shfl_xor(sum, 8, 64);
    sum += __shfl_xor(sum, 16, 64);
    sum += __shfl_xor(sum, 32, 64);     // per-r totals now in lanes 0..7
    if (o == 0) {                        // o=0: all r -> seg 0
        float tt = sum;
        tt += __shfl_xor(tt, 1, 64);
        tt += __shfl_xor(tt, 2, 64);
        tt += __shfl_xor(tt, 4, 64);
        if (lane == 0) cs0part[0] = tt;
    } else {
        if (lane == 0) cs0part[o] = sum;                     // r=0 -> seg 0 partial
        else if (lane < 8) atomicAdd(&colsum[o * lane], sum); // seg = o*r >= 1
    }
}

// ---------------- reduce cs0part -> colsum[0] ----------------
__global__ __launch_bounds__(256) void k_redcs(
    const float* __restrict__ cs0part, float* __restrict__ colsum)
{
    __shared__ float red[256];
    float sv = 0.f;
    for (int i = threadIdx.x; i < NN; i += 256) sv += cs0part[i];
    red[threadIdx.x] = sv;
    __syncthreads();
    for (int off = 128; off > 0; off >>= 1) {
        if (threadIdx.x < off) red[threadIdx.x] += red[threadIdx.x + off];
        __syncthreads();
    }
    if (threadIdx.x == 0) colsum[0] = red[0];
}

// ---------------- invert colsum in place ----------------
__global__ __launch_bounds__(256) void k_inv(float* __restrict__ cs)
{
    int i = blockIdx.x * blockDim.x + threadIdx.x;
    if (i < RP * NN) cs[i] = 1.0f / cs[i];
}

// ---------------- C1: per-object contributions (contiguous l1csc stream) ----------------
__global__ __launch_bounds__(256) void k_contrib(
    const float* __restrict__ l1csc, const float* __restrict__ ics,
    const int* __restrict__ cstart, const int* __restrict__ cscidx,
    const float* __restrict__ w1, __half* __restrict__ contrib)
{
    int o = (int)((blockIdx.x * blockDim.x + threadIdx.x) >> 6);
    int lane = threadIdx.x & 63;
    if (o >= NN) return;
    int qb = cstart[o], qe = cstart[o + 1];
    if (qb == qe) return;
    float y[8];
    y[0] = w1[lane] * ics[0];
#pragma unroll
    for (int r = 1; r < 8; ++r) {
        int seg = o * r;
        y[r] = w1[(size_t)seg * EMB + lane] * ics[seg];
    }
    for (int q = qb; q < qe; ++q) {
        const float4* lp4 = reinterpret_cast<const float4*>(l1csc + (size_t)q * 8);
        float4 A = lp4[0], B = lp4[1];
        float v = A.x * y[0];
        v = fmaf(A.y, y[1], v); v = fmaf(A.z, y[2], v); v = fmaf(A.w, y[3], v);
        v = fmaf(B.x, y[4], v); v = fmaf(B.y, y[5], v);
        v = fmaf(B.z, y[6], v); v = fmaf(B.w, y[7], v);
        int p = cscidx[q];
        contrib[(size_t)p * EMB + lane] = __float2half(v);   // scattered write: no stall
    }
}

// ---------------- C2 (fused): h = relu(bias + sum contrib)  +  rowsum pre-pass ----------------
__global__ __launch_bounds__(256) void k_h(
    const __half* __restrict__ contrib, const float* __restrict__ l2,
    const int* __restrict__ rowptr, const float* __restrict__ bias1,
    __half* __restrict__ h, float* __restrict__ rowsum, float* __restrict__ rs0part)
{
    int s = (int)((blockIdx.x * blockDim.x + threadIdx.x) >> 6);
    int lane = threadIdx.x & 63;
    if (s >= NN) return;
    int pb = rowptr[s], pe = rowptr[s + 1];
    float acc = 0.f;
    for (int p = pb; p < pe; ++p)
        acc += __half2float(contrib[(size_t)p * EMB + lane]);
    h[(size_t)s * EMB + lane] = __float2half(fmaxf(acc + bias1[lane], 0.f));

    float psum = 0.f;
    for (int p0 = pb + (lane >> 3); p0 < pe; p0 += 8)
        psum += l2[(size_t)p0 * 8 + (lane & 7)];
    psum += __shfl_xor(psum, 8, 64);
    psum += __shfl_xor(psum, 16, 64);
    psum += __shfl_xor(psum, 32, 64);
    if (s == 0) {
        float tt = psum;
        tt += __shfl_xor(tt, 1, 64);
        tt += __shfl_xor(tt, 2, 64);
        tt += __shfl_xor(tt, 4, 64);
        if (lane == 0) rs0part[0] = tt;
    } else {
        if (lane == 0) rs0part[s] = psum;
        else if (lane < 8) atomicAdd(&rowsum[s * lane], psum);
    }
}

// ---------------- reduce rs0part -> rowsum[0] (stored inverted) ----------------
__global__ __launch_bounds__(256) void k_redrs(
    const float* __restrict__ rs0part, float* __restrict__ rowsum)
{
    __shared__ float red[256];
    float sv = 0.f;
    for (int i = threadIdx.x; i < NN; i += 256) sv += rs0part[i];
    red[threadIdx.x] = sv;
    __syncthreads();
    for (int off = 128; off > 0; off >>= 1) {
        if (threadIdx.x < off) red[threadIdx.x] += red[threadIdx.x + off];
        __syncthreads();
    }
    if (threadIdx.x == 0) rowsum[0] = 1.0f / fmaxf(red[0], 1e-6f);
}

// ---------------- misc: invert rowsum[1..KMAX) + init out with bias2 ----------------
__global__ __launch_bounds__(256) void k_misc(
    float* __restrict__ rs, float* __restrict__ out, const float* __restrict__ b2)
{
    int i = blockIdx.x * blockDim.x + threadIdx.x;
    if (i >= 1 && i < KMAX) rs[i] = 1.0f / fmaxf(rs[i], 1e-6f);
    if (i < NN * NCLS) out[i] = b2[i & (NCLS - 1)];
}

// ---------------- D+E fused: per-s acc -> direct logits contribution ----------------
__global__ __launch_bounds__(256) void k_l2out(
    const float* __restrict__ l2, const int* __restrict__ rowptr,
    const int* __restrict__ vcol, const __half* __restrict__ h,
    const float* __restrict__ irs, const float* __restrict__ w2,
    float* __restrict__ out, float* __restrict__ Abuf0)
{
    int s = (int)((blockIdx.x * blockDim.x + threadIdx.x) >> 6);
    int lane = threadIdx.x & 63;
    if (s >= NN) return;
    int pb = rowptr[s], pe = rowptr[s + 1];
    // hoist the 7 irs loads: latency hides under the pair loop
    float sc[8];
#pragma unroll
    for (int rr = 1; rr < 8; ++rr) sc[rr] = (s > 0) ? irs[s * rr] : 0.f;
    float acc[8];
#pragma unroll
    for (int r = 0; r < 8; ++r) acc[r] = 0.f;
    int p = pb;
    for (; p + 3 < pe; p += 4) {            // unroll-4: four h gathers in flight
        int o0 = vcol[p], o1 = vcol[p + 1], o2 = vcol[p + 2], o3 = vcol[p + 3];
        float hv0 = __half2float(h[(size_t)o0 * EMB + lane]);
        float hv1 = __half2float(h[(size_t)o1 * EMB + lane]);
        float hv2 = __half2float(h[(size_t)o2 * EMB + lane]);
        float hv3 = __half2float(h[(size_t)o3 * EMB + lane]);
        const float4* q4 = reinterpret_cast<const float4*>(l2 + (size_t)p * 8);
        float4 A = q4[0], B = q4[1], C = q4[2], D = q4[3];
        float4 E = q4[4], F = q4[5], G = q4[6], H = q4[7];
        acc[0] = fmaf(A.x, hv0, fmaf(C.x, hv1, fmaf(E.x, hv2, fmaf(G.x, hv3, acc[0]))));
        acc[1] = fmaf(A.y, hv0, fmaf(C.y, hv1, fmaf(E.y, hv2, fmaf(G.y, hv3, acc[1]))));
        acc[2] = fmaf(A.z, hv0, fmaf(C.z, hv1, fmaf(E.z, hv2, fmaf(G.z, hv3, acc[2]))));
        acc[3] = fmaf(A.w, hv0, fmaf(C.w, hv1, fmaf(E.w, hv2, fmaf(G.w, hv3, acc[3]))));
        acc[4] = fmaf(B.x, hv0, fmaf(D.x, hv1, fmaf(F.x, hv2, fmaf(H.x, hv3, acc[4]))));
        acc[5] = fmaf(B.y, hv0, fmaf(D.y, hv1, fmaf(F.y, hv2, fmaf(H.y, hv3, acc[5]))));
        acc[6] = fmaf(B.z, hv0, fmaf(D.z, hv1, fmaf(F.z, hv2, fmaf(H.z, hv3, acc[6]))));
        acc[7] = fmaf(B.w, hv0, fmaf(D.w, hv1, fmaf(F.w, hv2, fmaf(H.w, hv3, acc[7]))));
    }
    for (; p < pe; ++p) {
        int o0 = vcol[p];
        float hv0 = __half2float(h[(size_t)o0 * EMB + lane]);
        const float4* q4 = reinterpret_cast<const float4*>(l2 + (size_t)p * 8);
        float4 A = q4[0], B = q4[1];
        acc[0] = fmaf(A.x, hv0, acc[0]); acc[1] = fmaf(A.y, hv0, acc[1]);
        acc[2] = fmaf(A.z, hv0, acc[2]); acc[3] = fmaf(A.w, hv0, acc[3]);
        acc[4] = fmaf(B.x, hv0, acc[4]); acc[5] = fmaf(B.y, hv0, acc[5]);
        acc[6] = fmaf(B.z, hv0, acc[6]); acc[7] = fmaf(B.w, hv0, acc[7]);
    }
    if (s == 0) {
        float a = acc[0] + acc[1] + acc[2] + acc[3] +
                  acc[4] + acc[5] + acc[6] + acc[7];
        Abuf0[lane] = a;
        return;
    }
    Abuf0[(size_t)s * EMB + lane] = acc[0];
    if (pb == pe) return;
    int hq = lane >> 4, c = lane & 15;
#pragma unroll
    for (int rr = 1; rr < 8; ++rr) {
        int k = s * rr;
        int rp = k / NN;
        int n  = k - rp * NN;
        float v = 0.f;
#pragma unroll
        for (int hh = 0; hh < 16; ++hh) {
            float av = __shfl(acc[rr], hq * 16 + hh, 64);
            v = fmaf(av, w2[((rp * EMB) + (hq * 16 + hh)) * NCLS + c], v);
        }
        v += __shfl_xor(v, 16, 64);
        v += __shfl_xor(v, 32, 64);
        if (lane < 16) atomicAdd(&out[(size_t)n * NCLS + lane], v * sc[rr]);
    }
}

// ---------------- reduce Abuf0 -> h0row ----------------
__global__ __launch_bounds__(256) void k_redA(
    const float* __restrict__ Abuf0, float* __restrict__ h0row)
{
    __shared__ float red[256];
    int lane = threadIdx.x & 63, w = threadIdx.x >> 6;
    float sum = 0.f;
    for (int ss = blockIdx.x + 64 * w; ss < NN; ss += 256)
        sum += Abuf0[(size_t)ss * EMB + lane];
    red[threadIdx.x] = sum;
    __syncthreads();
    if (threadIdx.x < 64) {
        float v = red[threadIdx.x] + red[threadIdx.x + 64] +
                  red[threadIdx.x + 128] + red[threadIdx.x + 192];
        atomicAdd(&h0row[threadIdx.x], v);
    }
}

// ---------------- k=0 logits contribution (n=0, rp=0) ----------------
__global__ __launch_bounds__(64) void k_out0(
    const float* __restrict__ h0row, const float* __restrict__ irs,
    const float* __restrict__ w2, float* __restrict__ out)
{
    int hq = threadIdx.x >> 4, c = threadIdx.x & 15;
    float v = 0.f;
#pragma unroll
    for (int hh = 0; hh < 16; ++hh) {
        int hd = hq * 16 + hh;
        v = fmaf(h0row[hd], w2[hd * NCLS + c], v);
    }
    v += __shfl_xor(v, 16, 64);
    v += __shfl_xor(v, 32, 64);
    if (threadIdx.x < 16) atomicAdd(&out[c], v * irs[0]);
}

extern "C" void kernel_launch(void* const* d_in, const int* in_sizes, int n_in,
                              void* d_out, int out_size, void* d_ws, size_t ws_size,
                              hipStream_t stream)
{
    const float* rm    = (const float*)d_in[0];
    const int*   hrow  = (const int*)d_in[1];   // sorted source nodes
    const int*   vcol  = (const int*)d_in[4];   // object nodes
    const float* W1    = (const float*)d_in[5];
    const float* b1    = (const float*)d_in[6];
    const float* W2    = (const float*)d_in[7];
    const float* b2    = (const float*)d_in[8];
    const float* w1    = (const float*)d_in[9];
    const float* w2    = (const float*)d_in[10];
    const float* bias1 = (const float*)d_in[11];
    const float* bias2 = (const float*)d_in[12];
    float* out = (float*)d_out;

    float* ws = (float*)d_ws;
    float*  l1csc   = ws;                       // [0, 2.00M)  CSC-ordered
    float*  l2      = ws + 2000000;             // [2.00M, 4.00M) p-order
    int*    rowptr  = (int*)(ws + 4000000);     // 20,001 ints
    float*  h0row   = ws + 4030000;             // 64
    float*  cs0part = ws + 4032000;             // 20,000
    float*  colsum  = ws + 4100000;             // 160,000 (inverted in place)
    float*  rowsum  = ws + 4260000;             // 140,000 (inverted in place)
    __half* h       = (__half*)(ws + 4400000);  // 1.28M halfs [4.40M, 5.04M)
    int*    cnt     = (int*)(ws + 5040000);     // 20,000
    int*    cstart  = cnt + 20000;              // 20,001
    int*    cnt2    = cstart + 20001;           // 20,000
    int*    cscidx  = cnt2 + 20000;             // 250,000 (ends 5.35M)
    int*    cscpos  = (int*)(ws + 5360000);     // 250,000 [5.36M, 5.61M)
    __half* contrib = (__half*)(ws + 5700000);  // 16M halfs [5.70M, 13.70M)
    // Abuf0/rs0part overlay l1csc (dead after k_contrib)
    float*  Abuf0   = ws;                       // 1.28M
    float*  rs0part = ws + 1280000;             // 20,000

    hipMemsetAsync(colsum, 0, (size_t)160000 * sizeof(float), stream);
    hipMemsetAsync(rowsum, 0, (size_t)KMAX * sizeof(float), stream);
    hipMemsetAsync(h0row, 0, (size_t)64 * sizeof(float), stream);
    hipMemsetAsync(cnt, 0, (size_t)20000 * sizeof(int), stream);

    k_rowptr <<<(NN + 256) / 256, 256, 0, stream>>>(hrow, rowptr);
    k_hist   <<<(NT + 255) / 256, 256, 0, stream>>>(vcol, cnt);
    k_scan   <<<1, 1024, 0, stream>>>(cnt, cstart, cnt2);
    k_pos    <<<(NT + 255) / 256, 256, 0, stream>>>(vcol, cnt2, cscidx, cscpos);
    k_gemv   <<<(NT + 255) / 256, 256, 0, stream>>>(rm, W1, b1, W2, b2, cscpos, l1csc, l2);
    k_colsum <<<(NN * 64) / 256, 256, 0, stream>>>(l1csc, cstart, colsum, cs0part);
    k_redcs  <<<1, 256, 0, stream>>>(cs0part, colsum);
    k_inv    <<<(RP * NN + 255) / 256, 256, 0, stream>>>(colsum);
    k_contrib<<<(NN * 64) / 256, 256, 0, stream>>>(l1csc, colsum, cstart, cscidx, w1, contrib);
    k_h      <<<(NN * 64) / 256, 256, 0, stream>>>(contrib, l2, rowptr, bias1, h, rowsum, rs0part);
    k_redrs  <<<1, 256, 0, stream>>>(rs0part, rowsum);
    k_misc   <<<(NN * NCLS + 255) / 256, 256, 0, stream>>>(rowsum, out, bias2);
    k_l2out  <<<(NN * 64) / 256, 256, 0, stream>>>(l2, rowptr, vcol, h, rowsum, w2, out, Abuf0);
    k_redA   <<<64, 256, 0, stream>>>(Abuf0, h0row);
    k_out0   <<<1, 64, 0, stream>>>(h0row, rowsum, w2, out);
}

// Round 13
// 264.912 us; speedup vs baseline: 1.0170x; 1.0170x over previous
//
#include <hip/hip_runtime.h>
#include <hip/hip_fp16.h>

#define NT      250000
#define NN      20000
#define RP      8
#define EMB     64
#define NCLS    16
#define NRELS   64
#define COLB    547       // ceil(NN*7/256)
#define REDB    64
#define KMAX    140000    // max segment id + 1 (19999*7 = 139993)

// ---------------- A: LDS-row-tiled per-thread GEMV + softmax ----------------
__global__ __launch_bounds__(256) void k_gemv(
    const float* __restrict__ rm,
    const float* __restrict__ W1, const float* __restrict__ b1,
    const float* __restrict__ W2, const float* __restrict__ b2,
    float* __restrict__ l1, float* __restrict__ l2)    // [NT][8] each
{
    __shared__ float tile[256 * 20];
    int t = threadIdx.x;
    int base = blockIdx.x * 256;
    float a1[8], a2[8];
#pragma unroll
    for (int r = 0; r < 8; ++r) { a1[r] = b1[r]; a2[r] = b2[r]; }

#pragma unroll 1
    for (int kc = 0; kc < 4; ++kc) {
        __syncthreads();
#pragma unroll
        for (int q = 0; q < 4; ++q) {
            int i = q * 256 + t;
            int pl = i >> 2, j4 = i & 3;
            int p = base + pl;
            float4 v = make_float4(0.f, 0.f, 0.f, 0.f);
            if (p < NT) v = reinterpret_cast<const float4*>(rm)[(size_t)p * 16 + kc * 4 + j4];
            *reinterpret_cast<float4*>(&tile[pl * 20 + j4 * 4]) = v;
        }
        __syncthreads();
        float xr[16];
#pragma unroll
        for (int j4 = 0; j4 < 4; ++j4) {
            float4 v = *reinterpret_cast<const float4*>(&tile[t * 20 + j4 * 4]);
            xr[j4 * 4 + 0] = v.x; xr[j4 * 4 + 1] = v.y;
            xr[j4 * 4 + 2] = v.z; xr[j4 * 4 + 3] = v.w;
        }
#pragma unroll
        for (int kk = 0; kk < 16; ++kk) {
            float x = xr[kk];
            int k = kc * 16 + kk;
#pragma unroll
            for (int r = 0; r < 8; ++r) {
                a1[r] = fmaf(x, W1[k * 8 + r], a1[r]);
                a2[r] = fmaf(x, W2[k * 8 + r], a2[r]);
            }
        }
    }
    int p = base + t;
    if (p >= NT) return;
    float mx = a2[0];
#pragma unroll
    for (int r = 1; r < 8; ++r) mx = fmaxf(mx, a2[r]);
    float sm = 0.f;
#pragma unroll
    for (int r = 0; r < 8; ++r) { a2[r] = __expf(a2[r] - mx); sm += a2[r]; }
    float inv = 1.0f / sm;
#pragma unroll
    for (int r = 0; r < 8; ++r) a2[r] *= inv;
    float4* o1 = reinterpret_cast<float4*>(l1 + (size_t)p * 8);
    float4* o2 = reinterpret_cast<float4*>(l2 + (size_t)p * 8);
    o1[0] = make_float4(a1[0], a1[1], a1[2], a1[3]);
    o1[1] = make_float4(a1[4], a1[5], a1[6], a1[7]);
    o2[0] = make_float4(a2[0], a2[1], a2[2], a2[3]);
    o2[1] = make_float4(a2[4], a2[5], a2[6], a2[7]);
}

// ---------------- CSR offsets (hrow sorted by np.unique) ----------------
__global__ __launch_bounds__(256) void k_rowptr(
    const int* __restrict__ hrow, int* __restrict__ rowptr)
{
    int i = blockIdx.x * blockDim.x + threadIdx.x;
    if (i > NN) return;
    int lo = 0, hi = NT;
    while (lo < hi) { int mid = (lo + hi) >> 1; if (hrow[mid] < i) lo = mid + 1; else hi = mid; }
    rowptr[i] = lo;
}

// ---------------- CSC build ----------------
__global__ __launch_bounds__(256) void k_hist(
    const int* __restrict__ vcol, int* __restrict__ cnt)
{
    int p = blockIdx.x * blockDim.x + threadIdx.x;
    if (p < NT) atomicAdd(&cnt[vcol[p]], 1);
}

__global__ __launch_bounds__(1024) void k_scan(
    const int* __restrict__ cnt, int* __restrict__ cstart, int* __restrict__ cnt2)
{
    __shared__ int part[1024];
    int t = threadIdx.x;
    int base = t * 20;
    int local[20];
    int s = 0;
#pragma unroll
    for (int i = 0; i < 20; ++i) {
        int idx = base + i;
        int c = (idx < NN) ? cnt[idx] : 0;
        local[i] = s;
        s += c;
    }
    part[t] = s;
    __syncthreads();
    for (int off = 1; off < 1024; off <<= 1) {
        int v = (t >= off) ? part[t - off] : 0;
        __syncthreads();
        part[t] += v;
        __syncthreads();
    }
    int ebase = t ? part[t - 1] : 0;
#pragma unroll
    for (int i = 0; i < 20; ++i) {
        int idx = base + i;
        if (idx < NN) { cstart[idx] = ebase + local[i]; cnt2[idx] = ebase + local[i]; }
    }
    if (t == 1023) cstart[NN] = part[1023];
}

__global__ __launch_bounds__(256) void k_pos(
    const int* __restrict__ vcol, int* __restrict__ cnt2, int* __restrict__ cscidx)
{
    int p = blockIdx.x * blockDim.x + threadIdx.x;
    if (p >= NT) return;
    int o = vcol[p];
    int slot = atomicAdd(&cnt2[o], 1);
    cscidx[slot] = p;
}

// ---------------- colsum via CSC gather-reduce ----------------
__global__ __launch_bounds__(256) void k_colsum(
    const float* __restrict__ l1, const int* __restrict__ cstart,
    const int* __restrict__ cscidx, float* __restrict__ colsum)
{
    int bid = blockIdx.x;
    if (bid < COLB) {
        int tid = bid * 256 + threadIdx.x;
        if (tid < NN * 7) {
            int o = tid / 7;
            int r = tid - o * 7 + 1;
            int qb = cstart[o], qe = cstart[o + 1];
            float s = 0.f;
            for (int q = qb; q < qe; ++q)
                s += l1[(size_t)cscidx[q] * 8 + r];
            atomicAdd(&colsum[o * r], s);
        }
    } else {
        int b2 = bid - COLB;
        float s = 0.f;
        for (int i = b2 * 256 + threadIdx.x; i < NT; i += REDB * 256) s += l1[(size_t)i * 8];
        __shared__ float red[256];
        red[threadIdx.x] = s;
        __syncthreads();
        for (int off = 128; off > 0; off >>= 1) {
            if (threadIdx.x < off) red[threadIdx.x] += red[threadIdx.x + off];
            __syncthreads();
        }
        if (threadIdx.x == 0) atomicAdd(&colsum[0], red[0]);
    }
}

// ---------------- invert colsum in place ----------------
__global__ __launch_bounds__(256) void k_inv(float* __restrict__ cs)
{
    int i = blockIdx.x * blockDim.x + threadIdx.x;
    if (i < RP * NN) cs[i] = 1.0f / cs[i];
}

// ---------------- C1: per-object contributions (one wave per o) ----------------
__global__ __launch_bounds__(256) void k_contrib(
    const float* __restrict__ l1, const float* __restrict__ ics,
    const int* __restrict__ cstart, const int* __restrict__ cscidx,
    const float* __restrict__ w1, __half* __restrict__ contrib)
{
    int o = (int)((blockIdx.x * blockDim.x + threadIdx.x) >> 6);
    int lane = threadIdx.x & 63;
    if (o >= NN) return;
    int qb = cstart[o], qe = cstart[o + 1];
    if (qb == qe) return;
    float y[8];
    y[0] = w1[lane] * ics[0];
#pragma unroll
    for (int r = 1; r < 8; ++r) {
        int seg = o * r;
        y[r] = w1[(size_t)seg * EMB + lane] * ics[seg];
    }
    for (int q = qb; q < qe; ++q) {
        int p = cscidx[q];
        const float4* lp4 = reinterpret_cast<const float4*>(l1 + (size_t)p * 8);
        float4 A = lp4[0], B = lp4[1];
        float v = A.x * y[0];
        v = fmaf(A.y, y[1], v); v = fmaf(A.z, y[2], v); v = fmaf(A.w, y[3], v);
        v = fmaf(B.x, y[4], v); v = fmaf(B.y, y[5], v);
        v = fmaf(B.z, y[6], v); v = fmaf(B.w, y[7], v);
        contrib[(size_t)p * EMB + lane] = __float2half(v);
    }
}

// ---------------- C2 (fused): h = relu(bias + sum contrib) + rowsum pre-pass ----------------
__global__ __launch_bounds__(256) void k_h(
    const __half* __restrict__ contrib, const float* __restrict__ l2,
    const int* __restrict__ rowptr, const float* __restrict__ bias1,
    __half* __restrict__ h, float* __restrict__ rowsum, float* __restrict__ rs0part)
{
    int s = (int)((blockIdx.x * blockDim.x + threadIdx.x) >> 6);
    int lane = threadIdx.x & 63;
    if (s >= NN) return;
    int pb = rowptr[s], pe = rowptr[s + 1];
    float acc = 0.f;
    for (int p = pb; p < pe; ++p)
        acc += __half2float(contrib[(size_t)p * EMB + lane]);
    h[(size_t)s * EMB + lane] = __float2half(fmaxf(acc + bias1[lane], 0.f));

    float psum = 0.f;
    for (int p0 = pb + (lane >> 3); p0 < pe; p0 += 8)
        psum += l2[(size_t)p0 * 8 + (lane & 7)];
    psum += __shfl_xor(psum, 8, 64);
    psum += __shfl_xor(psum, 16, 64);
    psum += __shfl_xor(psum, 32, 64);
    if (s == 0) {
        float tt = psum;
        tt += __shfl_xor(tt, 1, 64);
        tt += __shfl_xor(tt, 2, 64);
        tt += __shfl_xor(tt, 4, 64);
        if (lane == 0) rs0part[0] = tt;
    } else {
        if (lane == 0) rs0part[s] = psum;
        else if (lane < 8) atomicAdd(&rowsum[s * lane], psum);
    }
}

// ---------------- reduce rs0part -> rowsum[0] (stored inverted) ----------------
__global__ __launch_bounds__(256) void k_redrs(
    const float* __restrict__ rs0part, float* __restrict__ rowsum)
{
    __shared__ float red[256];
    float sv = 0.f;
    for (int i = threadIdx.x; i < NN; i += 256) sv += rs0part[i];
    red[threadIdx.x] = sv;
    __syncthreads();
    for (int off = 128; off > 0; off >>= 1) {
        if (threadIdx.x < off) red[threadIdx.x] += red[threadIdx.x + off];
        __syncthreads();
    }
    if (threadIdx.x == 0) rowsum[0] = 1.0f / fmaxf(red[0], 1e-6f);
}

// ---------------- misc: invert rowsum[1..KMAX) + init out with bias2 ----------------
__global__ __launch_bounds__(256) void k_misc(
    float* __restrict__ rs, float* __restrict__ out, const float* __restrict__ b2)
{
    int i = blockIdx.x * blockDim.x + threadIdx.x;
    if (i >= 1 && i < KMAX) rs[i] = 1.0f / fmaxf(rs[i], 1e-6f);
    if (i < NN * NCLS) out[i] = b2[i & (NCLS - 1)];
}

// ---------------- D+E fused v2: 2 waves per s, LDS combine, split einsum tail ----------------
__global__ __launch_bounds__(256) void k_l2out(
    const float* __restrict__ l2, const int* __restrict__ rowptr,
    const int* __restrict__ vcol, const __half* __restrict__ h,
    const float* __restrict__ irs, const float* __restrict__ w2,
    float* __restrict__ out, float* __restrict__ Abuf0)
{
    __shared__ float lacc[4][8 * 64];     // 8 KB
    int w = threadIdx.x >> 6;
    int lane = threadIdx.x & 63;
    int g = w >> 1, sub = w & 1;
    int s = blockIdx.x * 2 + g;           // grid = NN/2 -> s < NN exactly
    int pb = rowptr[s], pe = rowptr[s + 1];
    // hoist irs loads: latency hides under the pair loop
    float sc[8];
#pragma unroll
    for (int rr = 1; rr < 8; ++rr) sc[rr] = (s > 0) ? irs[s * rr] : 0.f;
    float acc[8];
#pragma unroll
    for (int r = 0; r < 8; ++r) acc[r] = 0.f;
    int half = (pe - pb + 1) >> 1;
    int mb = pb + sub * half;
    int me = sub ? pe : pb + half;
    int p = mb;
    for (; p + 3 < me; p += 4) {          // four h gathers in flight
        int o0 = vcol[p], o1 = vcol[p + 1], o2 = vcol[p + 2], o3 = vcol[p + 3];
        float hv0 = __half2float(h[(size_t)o0 * EMB + lane]);
        float hv1 = __half2float(h[(size_t)o1 * EMB + lane]);
        float hv2 = __half2float(h[(size_t)o2 * EMB + lane]);
        float hv3 = __half2float(h[(size_t)o3 * EMB + lane]);
        const float4* q4 = reinterpret_cast<const float4*>(l2 + (size_t)p * 8);
        float4 A = q4[0], B = q4[1], C = q4[2], D = q4[3];
        float4 E = q4[4], F = q4[5], G = q4[6], H = q4[7];
        acc[0] = fmaf(A.x, hv0, fmaf(C.x, hv1, fmaf(E.x, hv2, fmaf(G.x, hv3, acc[0]))));
        acc[1] = fmaf(A.y, hv0, fmaf(C.y, hv1, fmaf(E.y, hv2, fmaf(G.y, hv3, acc[1]))));
        acc[2] = fmaf(A.z, hv0, fmaf(C.z, hv1, fmaf(E.z, hv2, fmaf(G.z, hv3, acc[2]))));
        acc[3] = fmaf(A.w, hv0, fmaf(C.w, hv1, fmaf(E.w, hv2, fmaf(G.w, hv3, acc[3]))));
        acc[4] = fmaf(B.x, hv0, fmaf(D.x, hv1, fmaf(F.x, hv2, fmaf(H.x, hv3, acc[4]))));
        acc[5] = fmaf(B.y, hv0, fmaf(D.y, hv1, fmaf(F.y, hv2, fmaf(H.y, hv3, acc[5]))));
        acc[6] = fmaf(B.z, hv0, fmaf(D.z, hv1, fmaf(F.z, hv2, fmaf(H.z, hv3, acc[6]))));
        acc[7] = fmaf(B.w, hv0, fmaf(D.w, hv1, fmaf(F.w, hv2, fmaf(H.w, hv3, acc[7]))));
    }
    for (; p < me; ++p) {
        int o0 = vcol[p];
        float hv0 = __half2float(h[(size_t)o0 * EMB + lane]);
        const float4* q4 = reinterpret_cast<const float4*>(l2 + (size_t)p * 8);
        float4 A = q4[0], B = q4[1];
        acc[0] = fmaf(A.x, hv0, acc[0]); acc[1] = fmaf(A.y, hv0, acc[1]);
        acc[2] = fmaf(A.z, hv0, acc[2]); acc[3] = fmaf(A.w, hv0, acc[3]);
        acc[4] = fmaf(B.x, hv0, acc[4]); acc[5] = fmaf(B.y, hv0, acc[5]);
        acc[6] = fmaf(B.z, hv0, acc[6]); acc[7] = fmaf(B.w, hv0, acc[7]);
    }
#pragma unroll
    for (int r = 0; r < 8; ++r) lacc[w][r * 64 + lane] = acc[r];
    __syncthreads();
    float ca[8];
#pragma unroll
    for (int r = 0; r < 8; ++r)
        ca[r] = lacc[2 * g][r * 64 + lane] + lacc[2 * g + 1][r * 64 + lane];
    if (s == 0) {                          // all 8 r -> k=0: park total
        if (sub == 0) {
            float a = ca[0] + ca[1] + ca[2] + ca[3] + ca[4] + ca[5] + ca[6] + ca[7];
            Abuf0[lane] = a;
        }
        return;
    }
    if (sub == 0) Abuf0[(size_t)s * EMB + lane] = ca[0];   // r=0 -> k=0 partial
    if (pb == pe) return;
    int hq = lane >> 4, c = lane & 15;
    int rlo = sub ? 4 : 1, rhi = sub ? 8 : 4;
    for (int rr = rlo; rr < rhi; ++rr) {
        int k = s * rr;
        int rp = k / NN;
        int n  = k - rp * NN;
        float a = ca[rr];
        float v = 0.f;
#pragma unroll
        for (int hh = 0; hh < 16; ++hh) {
            float av = __shfl(a, hq * 16 + hh, 64);
            v = fmaf(av, w2[((rp * EMB) + (hq * 16 + hh)) * NCLS + c], v);
        }
        v += __shfl_xor(v, 16, 64);
        v += __shfl_xor(v, 32, 64);
        if (lane < 16) atomicAdd(&out[(size_t)n * NCLS + lane], v * sc[rr]);
    }
}

// ---------------- reduce Abuf0 -> h0row ----------------
__global__ __launch_bounds__(256) void k_redA(
    const float* __restrict__ Abuf0, float* __restrict__ h0row)
{
    __shared__ float red[256];
    int lane = threadIdx.x & 63, w = threadIdx.x >> 6;
    float sum = 0.f;
    for (int ss = blockIdx.x + 64 * w; ss < NN; ss += 256)
        sum += Abuf0[(size_t)ss * EMB + lane];
    red[threadIdx.x] = sum;
    __syncthreads();
    if (threadIdx.x < 64) {
        float v = red[threadIdx.x] + red[threadIdx.x + 64] +
                  red[threadIdx.x + 128] + red[threadIdx.x + 192];
        atomicAdd(&h0row[threadIdx.x], v);
    }
}

// ---------------- k=0 logits contribution (n=0, rp=0) ----------------
__global__ __launch_bounds__(64) void k_out0(
    const float* __restrict__ h0row, const float* __restrict__ irs0,
    const float* __restrict__ w2, float* __restrict__ out)
{
    int hq = threadIdx.x >> 4, c = threadIdx.x & 15;
    float v = 0.f;
#pragma unroll
    for (int hh = 0; hh < 16; ++hh) {
        int hd = hq * 16 + hh;
        v = fmaf(h0row[hd], w2[hd * NCLS + c], v);
    }
    v += __shfl_xor(v, 16, 64);
    v += __shfl_xor(v, 32, 64);
    if (threadIdx.x < 16) atomicAdd(&out[c], v * irs0[0]);
}

extern "C" void kernel_launch(void* const* d_in, const int* in_sizes, int n_in,
                              void* d_out, int out_size, void* d_ws, size_t ws_size,
                              hipStream_t stream)
{
    const float* rm    = (const float*)d_in[0];
    const int*   hrow  = (const int*)d_in[1];   // sorted source nodes
    const int*   vcol  = (const int*)d_in[4];   // object nodes
    const float* W1    = (const float*)d_in[5];
    const float* b1    = (const float*)d_in[6];
    const float* W2    = (const float*)d_in[7];
    const float* b2    = (const float*)d_in[8];
    const float* w1    = (const float*)d_in[9];
    const float* w2    = (const float*)d_in[10];
    const float* bias1 = (const float*)d_in[11];
    const float* bias2 = (const float*)d_in[12];
    float* out = (float*)d_out;

    float* ws = (float*)d_ws;
    float*  l1      = ws;                       // [0, 2.00M)
    float*  l2      = ws + 2000000;             // [2.00M, 4.00M)
    int*    rowptr  = (int*)(ws + 4000000);     // 20,001 ints
    float*  h0row   = ws + 4030000;             // 64
    float*  colsum  = ws + 4100000;             // 160,000 (inverted in place)
    float*  rowsum  = ws + 4260000;             // 140,000 (inverted in place)
    __half* h       = (__half*)(ws + 4400000);  // 1.28M halfs [4.40M, 5.04M)
    int*    cnt     = (int*)(ws + 5040000);     // 20,000
    int*    cstart  = cnt + 20000;              // 20,001
    int*    cnt2    = cstart + 20001;           // 20,000
    int*    cscidx  = cnt2 + 20000;             // 250,000 (ends 5.35M)
    __half* contrib = (__half*)(ws + 5600000);  // 16M halfs [5.60M, 13.60M)
    // Abuf0/rs0part overlay l1 (l1 dead after k_contrib)
    float*  Abuf0   = ws;                       // 1.28M
    float*  rs0part = ws + 1280000;             // 20,000

    hipMemsetAsync(colsum, 0, (size_t)160000 * sizeof(float), stream);
    hipMemsetAsync(rowsum, 0, (size_t)KMAX * sizeof(float), stream);
    hipMemsetAsync(h0row, 0, (size_t)64 * sizeof(float), stream);
    hipMemsetAsync(cnt, 0, (size_t)20000 * sizeof(int), stream);

    k_rowptr <<<(NN + 256) / 256, 256, 0, stream>>>(hrow, rowptr);
    k_hist   <<<(NT + 255) / 256, 256, 0, stream>>>(vcol, cnt);
    k_scan   <<<1, 1024, 0, stream>>>(cnt, cstart, cnt2);
    k_pos    <<<(NT + 255) / 256, 256, 0, stream>>>(vcol, cnt2, cscidx);
    k_gemv   <<<(NT + 255) / 256, 256, 0, stream>>>(rm, W1, b1, W2, b2, l1, l2);
    k_colsum <<<COLB + REDB, 256, 0, stream>>>(l1, cstart, cscidx, colsum);
    k_inv    <<<(RP * NN + 255) / 256, 256, 0, stream>>>(colsum);
    k_contrib<<<(NN * 64) / 256, 256, 0, stream>>>(l1, colsum, cstart, cscidx, w1, contrib);
    k_h      <<<(NN * 64) / 256, 256, 0, stream>>>(contrib, l2, rowptr, bias1, h, rowsum, rs0part);
    k_redrs  <<<1, 256, 0, stream>>>(rs0part, rowsum);
    k_misc   <<<(NN * NCLS + 255) / 256, 256, 0, stream>>>(rowsum, out, bias2);
    k_l2out  <<<NN / 2, 256, 0, stream>>>(l2, rowptr, vcol, h, rowsum, w2, out, Abuf0);
    k_redA   <<<64, 256, 0, stream>>>(Abuf0, h0row);
    k_out0   <<<1, 64, 0, stream>>>(h0row, rowsum, w2, out);
}

// Round 14
// 251.278 us; speedup vs baseline: 1.0722x; 1.0543x over previous
//
#include <hip/hip_runtime.h>
#include <hip/hip_fp16.h>

#define NT      250000
#define NN      20000
#define RP      8
#define EMB     64
#define NCLS    16
#define NRELS   64
#define COLB    547       // ceil(NN*7/256)
#define REDB    64
#define KMAX    140000    // max segment id + 1 (19999*7 = 139993)
#define RPB     79        // blocks for rowptr part
#define HIB     977       // blocks for hist part
#define MISCB   1250      // blocks for invert+outinit part

// ---------------- A: LDS-row-tiled per-thread GEMV + softmax ----------------
__global__ __launch_bounds__(256) void k_gemv(
    const float* __restrict__ rm,
    const float* __restrict__ W1, const float* __restrict__ b1,
    const float* __restrict__ W2, const float* __restrict__ b2,
    float* __restrict__ l1, float* __restrict__ l2)    // [NT][8] each
{
    __shared__ float tile[256 * 20];
    int t = threadIdx.x;
    int base = blockIdx.x * 256;
    float a1[8], a2[8];
#pragma unroll
    for (int r = 0; r < 8; ++r) { a1[r] = b1[r]; a2[r] = b2[r]; }

#pragma unroll 1
    for (int kc = 0; kc < 4; ++kc) {
        __syncthreads();
#pragma unroll
        for (int q = 0; q < 4; ++q) {
            int i = q * 256 + t;
            int pl = i >> 2, j4 = i & 3;
            int p = base + pl;
            float4 v = make_float4(0.f, 0.f, 0.f, 0.f);
            if (p < NT) v = reinterpret_cast<const float4*>(rm)[(size_t)p * 16 + kc * 4 + j4];
            *reinterpret_cast<float4*>(&tile[pl * 20 + j4 * 4]) = v;
        }
        __syncthreads();
        float xr[16];
#pragma unroll
        for (int j4 = 0; j4 < 4; ++j4) {
            float4 v = *reinterpret_cast<const float4*>(&tile[t * 20 + j4 * 4]);
            xr[j4 * 4 + 0] = v.x; xr[j4 * 4 + 1] = v.y;
            xr[j4 * 4 + 2] = v.z; xr[j4 * 4 + 3] = v.w;
        }
#pragma unroll
        for (int kk = 0; kk < 16; ++kk) {
            float x = xr[kk];
            int k = kc * 16 + kk;
#pragma unroll
            for (int r = 0; r < 8; ++r) {
                a1[r] = fmaf(x, W1[k * 8 + r], a1[r]);
                a2[r] = fmaf(x, W2[k * 8 + r], a2[r]);
            }
        }
    }
    int p = base + t;
    if (p >= NT) return;
    float mx = a2[0];
#pragma unroll
    for (int r = 1; r < 8; ++r) mx = fmaxf(mx, a2[r]);
    float sm = 0.f;
#pragma unroll
    for (int r = 0; r < 8; ++r) { a2[r] = __expf(a2[r] - mx); sm += a2[r]; }
    float inv = 1.0f / sm;
#pragma unroll
    for (int r = 0; r < 8; ++r) a2[r] *= inv;
    float4* o1 = reinterpret_cast<float4*>(l1 + (size_t)p * 8);
    float4* o2 = reinterpret_cast<float4*>(l2 + (size_t)p * 8);
    o1[0] = make_float4(a1[0], a1[1], a1[2], a1[3]);
    o1[1] = make_float4(a1[4], a1[5], a1[6], a1[7]);
    o2[0] = make_float4(a2[0], a2[1], a2[2], a2[3]);
    o2[1] = make_float4(a2[4], a2[5], a2[6], a2[7]);
}

// ---------------- fused: CSR offsets (binary search) + vcol histogram ----------------
__global__ __launch_bounds__(256) void k_init(
    const int* __restrict__ hrow, int* __restrict__ rowptr,
    const int* __restrict__ vcol, int* __restrict__ cnt)
{
    int bid = blockIdx.x;
    if (bid < RPB) {
        int i = bid * 256 + threadIdx.x;
        if (i > NN) return;
        int lo = 0, hi = NT;
        while (lo < hi) { int mid = (lo + hi) >> 1; if (hrow[mid] < i) lo = mid + 1; else hi = mid; }
        rowptr[i] = lo;
    } else {
        int p = (bid - RPB) * 256 + threadIdx.x;
        if (p < NT) atomicAdd(&cnt[vcol[p]], 1);
    }
}

__global__ __launch_bounds__(1024) void k_scan(
    const int* __restrict__ cnt, int* __restrict__ cstart, int* __restrict__ cnt2)
{
    __shared__ int part[1024];
    int t = threadIdx.x;
    int base = t * 20;
    int local[20];
    int s = 0;
#pragma unroll
    for (int i = 0; i < 20; ++i) {
        int idx = base + i;
        int c = (idx < NN) ? cnt[idx] : 0;
        local[i] = s;
        s += c;
    }
    part[t] = s;
    __syncthreads();
    for (int off = 1; off < 1024; off <<= 1) {
        int v = (t >= off) ? part[t - off] : 0;
        __syncthreads();
        part[t] += v;
        __syncthreads();
    }
    int ebase = t ? part[t - 1] : 0;
#pragma unroll
    for (int i = 0; i < 20; ++i) {
        int idx = base + i;
        if (idx < NN) { cstart[idx] = ebase + local[i]; cnt2[idx] = ebase + local[i]; }
    }
    if (t == 1023) cstart[NN] = part[1023];
}

__global__ __launch_bounds__(256) void k_pos(
    const int* __restrict__ vcol, int* __restrict__ cnt2, int* __restrict__ cscidx)
{
    int p = blockIdx.x * blockDim.x + threadIdx.x;
    if (p >= NT) return;
    int o = vcol[p];
    int slot = atomicAdd(&cnt2[o], 1);
    cscidx[slot] = p;
}

// ---------------- colsum via CSC gather-reduce ----------------
__global__ __launch_bounds__(256) void k_colsum(
    const float* __restrict__ l1, const int* __restrict__ cstart,
    const int* __restrict__ cscidx, float* __restrict__ colsum)
{
    int bid = blockIdx.x;
    if (bid < COLB) {
        int tid = bid * 256 + threadIdx.x;
        if (tid < NN * 7) {
            int o = tid / 7;
            int r = tid - o * 7 + 1;
            int qb = cstart[o], qe = cstart[o + 1];
            float s = 0.f;
            for (int q = qb; q < qe; ++q)
                s += l1[(size_t)cscidx[q] * 8 + r];
            atomicAdd(&colsum[o * r], s);
        }
    } else {
        int b2 = bid - COLB;
        float s = 0.f;
        for (int i = b2 * 256 + threadIdx.x; i < NT; i += REDB * 256) s += l1[(size_t)i * 8];
        __shared__ float red[256];
        red[threadIdx.x] = s;
        __syncthreads();
        for (int off = 128; off > 0; off >>= 1) {
            if (threadIdx.x < off) red[threadIdx.x] += red[threadIdx.x + off];
            __syncthreads();
        }
        if (threadIdx.x == 0) atomicAdd(&colsum[0], red[0]);
    }
}

// ---------------- invert colsum in place ----------------
__global__ __launch_bounds__(256) void k_inv(float* __restrict__ cs)
{
    int i = blockIdx.x * blockDim.x + threadIdx.x;
    if (i < RP * NN) cs[i] = 1.0f / cs[i];
}

// ---------------- C1: per-object contributions (unroll-2 gathers) ----------------
__global__ __launch_bounds__(256) void k_contrib(
    const float* __restrict__ l1, const float* __restrict__ ics,
    const int* __restrict__ cstart, const int* __restrict__ cscidx,
    const float* __restrict__ w1, __half* __restrict__ contrib)
{
    int o = (int)((blockIdx.x * blockDim.x + threadIdx.x) >> 6);
    int lane = threadIdx.x & 63;
    if (o >= NN) return;
    int qb = cstart[o], qe = cstart[o + 1];
    if (qb == qe) return;
    float y[8];
    y[0] = w1[lane] * ics[0];
#pragma unroll
    for (int r = 1; r < 8; ++r) {
        int seg = o * r;
        y[r] = w1[(size_t)seg * EMB + lane] * ics[seg];
    }
    int q = qb;
    for (; q + 1 < qe; q += 2) {          // two l1 gathers in flight
        int p0 = cscidx[q], p1 = cscidx[q + 1];
        const float4* a4 = reinterpret_cast<const float4*>(l1 + (size_t)p0 * 8);
        const float4* b4 = reinterpret_cast<const float4*>(l1 + (size_t)p1 * 8);
        float4 A = a4[0], B = a4[1], C = b4[0], D = b4[1];
        float v0 = A.x * y[0];
        v0 = fmaf(A.y, y[1], v0); v0 = fmaf(A.z, y[2], v0); v0 = fmaf(A.w, y[3], v0);
        v0 = fmaf(B.x, y[4], v0); v0 = fmaf(B.y, y[5], v0);
        v0 = fmaf(B.z, y[6], v0); v0 = fmaf(B.w, y[7], v0);
        float v1 = C.x * y[0];
        v1 = fmaf(C.y, y[1], v1); v1 = fmaf(C.z, y[2], v1); v1 = fmaf(C.w, y[3], v1);
        v1 = fmaf(D.x, y[4], v1); v1 = fmaf(D.y, y[5], v1);
        v1 = fmaf(D.z, y[6], v1); v1 = fmaf(D.w, y[7], v1);
        contrib[(size_t)p0 * EMB + lane] = __float2half(v0);
        contrib[(size_t)p1 * EMB + lane] = __float2half(v1);
    }
    if (q < qe) {
        int p0 = cscidx[q];
        const float4* a4 = reinterpret_cast<const float4*>(l1 + (size_t)p0 * 8);
        float4 A = a4[0], B = a4[1];
        float v0 = A.x * y[0];
        v0 = fmaf(A.y, y[1], v0); v0 = fmaf(A.z, y[2], v0); v0 = fmaf(A.w, y[3], v0);
        v0 = fmaf(B.x, y[4], v0); v0 = fmaf(B.y, y[5], v0);
        v0 = fmaf(B.z, y[6], v0); v0 = fmaf(B.w, y[7], v0);
        contrib[(size_t)p0 * EMB + lane] = __float2half(v0);
    }
}

// ---------------- C2 (fused): h = relu(bias + sum contrib) + rowsum pre-pass ----------------
__global__ __launch_bounds__(256) void k_h(
    const __half* __restrict__ contrib, const float* __restrict__ l2,
    const int* __restrict__ rowptr, const float* __restrict__ bias1,
    __half* __restrict__ h, float* __restrict__ rowsum, float* __restrict__ rs0part)
{
    int s = (int)((blockIdx.x * blockDim.x + threadIdx.x) >> 6);
    int lane = threadIdx.x & 63;
    if (s >= NN) return;
    int pb = rowptr[s], pe = rowptr[s + 1];
    float acc = 0.f;
    for (int p = pb; p < pe; ++p)
        acc += __half2float(contrib[(size_t)p * EMB + lane]);
    h[(size_t)s * EMB + lane] = __float2half(fmaxf(acc + bias1[lane], 0.f));

    float psum = 0.f;
    for (int p0 = pb + (lane >> 3); p0 < pe; p0 += 8)
        psum += l2[(size_t)p0 * 8 + (lane & 7)];
    psum += __shfl_xor(psum, 8, 64);
    psum += __shfl_xor(psum, 16, 64);
    psum += __shfl_xor(psum, 32, 64);
    if (s == 0) {
        float tt = psum;
        tt += __shfl_xor(tt, 1, 64);
        tt += __shfl_xor(tt, 2, 64);
        tt += __shfl_xor(tt, 4, 64);
        if (lane == 0) rs0part[0] = tt;
    } else {
        if (lane == 0) rs0part[s] = psum;
        else if (lane < 8) atomicAdd(&rowsum[s * lane], psum);
    }
}

// ---------------- fused: rowsum inversion + out=bias2 init + rs0 reduce ----------------
__global__ __launch_bounds__(256) void k_misc(
    float* __restrict__ rs, float* __restrict__ out, const float* __restrict__ b2,
    const float* __restrict__ rs0part)
{
    int bid = blockIdx.x;
    if (bid < MISCB) {
        int i = bid * 256 + threadIdx.x;
        if (i >= 1 && i < KMAX) rs[i] = 1.0f / fmaxf(rs[i], 1e-6f);
        if (i < NN * NCLS) out[i] = b2[i & (NCLS - 1)];
    } else {
        __shared__ float red[256];
        float sv = 0.f;
        for (int i = threadIdx.x; i < NN; i += 256) sv += rs0part[i];
        red[threadIdx.x] = sv;
        __syncthreads();
        for (int off = 128; off > 0; off >>= 1) {
            if (threadIdx.x < off) red[threadIdx.x] += red[threadIdx.x + off];
            __syncthreads();
        }
        if (threadIdx.x == 0) rs[0] = 1.0f / fmaxf(red[0], 1e-6f);
    }
}

// ---------------- D+E fused: single wave per s, unroll-4, hoisted irs ----------------
__global__ __launch_bounds__(256) void k_l2out(
    const float* __restrict__ l2, const int* __restrict__ rowptr,
    const int* __restrict__ vcol, const __half* __restrict__ h,
    const float* __restrict__ irs, const float* __restrict__ w2,
    float* __restrict__ out, float* __restrict__ Abuf0)
{
    int s = (int)((blockIdx.x * blockDim.x + threadIdx.x) >> 6);
    int lane = threadIdx.x & 63;
    if (s >= NN) return;
    int pb = rowptr[s], pe = rowptr[s + 1];
    float sc[8];
#pragma unroll
    for (int rr = 1; rr < 8; ++rr) sc[rr] = (s > 0) ? irs[s * rr] : 0.f;
    float acc[8];
#pragma unroll
    for (int r = 0; r < 8; ++r) acc[r] = 0.f;
    int p = pb;
    for (; p + 3 < pe; p += 4) {            // four h gathers in flight
        int o0 = vcol[p], o1 = vcol[p + 1], o2 = vcol[p + 2], o3 = vcol[p + 3];
        float hv0 = __half2float(h[(size_t)o0 * EMB + lane]);
        float hv1 = __half2float(h[(size_t)o1 * EMB + lane]);
        float hv2 = __half2float(h[(size_t)o2 * EMB + lane]);
        float hv3 = __half2float(h[(size_t)o3 * EMB + lane]);
        const float4* q4 = reinterpret_cast<const float4*>(l2 + (size_t)p * 8);
        float4 A = q4[0], B = q4[1], C = q4[2], D = q4[3];
        float4 E = q4[4], F = q4[5], G = q4[6], H = q4[7];
        acc[0] = fmaf(A.x, hv0, fmaf(C.x, hv1, fmaf(E.x, hv2, fmaf(G.x, hv3, acc[0]))));
        acc[1] = fmaf(A.y, hv0, fmaf(C.y, hv1, fmaf(E.y, hv2, fmaf(G.y, hv3, acc[1]))));
        acc[2] = fmaf(A.z, hv0, fmaf(C.z, hv1, fmaf(E.z, hv2, fmaf(G.z, hv3, acc[2]))));
        acc[3] = fmaf(A.w, hv0, fmaf(C.w, hv1, fmaf(E.w, hv2, fmaf(G.w, hv3, acc[3]))));
        acc[4] = fmaf(B.x, hv0, fmaf(D.x, hv1, fmaf(F.x, hv2, fmaf(H.x, hv3, acc[4]))));
        acc[5] = fmaf(B.y, hv0, fmaf(D.y, hv1, fmaf(F.y, hv2, fmaf(H.y, hv3, acc[5]))));
        acc[6] = fmaf(B.z, hv0, fmaf(D.z, hv1, fmaf(F.z, hv2, fmaf(H.z, hv3, acc[6]))));
        acc[7] = fmaf(B.w, hv0, fmaf(D.w, hv1, fmaf(F.w, hv2, fmaf(H.w, hv3, acc[7]))));
    }
    for (; p < pe; ++p) {
        int o0 = vcol[p];
        float hv0 = __half2float(h[(size_t)o0 * EMB + lane]);
        const float4* q4 = reinterpret_cast<const float4*>(l2 + (size_t)p * 8);
        float4 A = q4[0], B = q4[1];
        acc[0] = fmaf(A.x, hv0, acc[0]); acc[1] = fmaf(A.y, hv0, acc[1]);
        acc[2] = fmaf(A.z, hv0, acc[2]); acc[3] = fmaf(A.w, hv0, acc[3]);
        acc[4] = fmaf(B.x, hv0, acc[4]); acc[5] = fmaf(B.y, hv0, acc[5]);
        acc[6] = fmaf(B.z, hv0, acc[6]); acc[7] = fmaf(B.w, hv0, acc[7]);
    }
    if (s == 0) {
        float a = acc[0] + acc[1] + acc[2] + acc[3] +
                  acc[4] + acc[5] + acc[6] + acc[7];
        Abuf0[lane] = a;
        return;
    }
    Abuf0[(size_t)s * EMB + lane] = acc[0];
    if (pb == pe) return;
    int hq = lane >> 4, c = lane & 15;
#pragma unroll
    for (int rr = 1; rr < 8; ++rr) {
        int k = s * rr;
        int rp = k / NN;
        int n  = k - rp * NN;
        float v = 0.f;
#pragma unroll
        for (int hh = 0; hh < 16; ++hh) {
            float av = __shfl(acc[rr], hq * 16 + hh, 64);
            v = fmaf(av, w2[((rp * EMB) + (hq * 16 + hh)) * NCLS + c], v);
        }
        v += __shfl_xor(v, 16, 64);
        v += __shfl_xor(v, 32, 64);
        if (lane < 16) atomicAdd(&out[(size_t)n * NCLS + lane], v * sc[rr]);
    }
}

// ---------------- reduce Abuf0 -> h0row ----------------
__global__ __launch_bounds__(256) void k_redA(
    const float* __restrict__ Abuf0, float* __restrict__ h0row)
{
    __shared__ float red[256];
    int lane = threadIdx.x & 63, w = threadIdx.x >> 6;
    float sum = 0.f;
    for (int ss = blockIdx.x + 64 * w; ss < NN; ss += 256)
        sum += Abuf0[(size_t)ss * EMB + lane];
    red[threadIdx.x] = sum;
    __syncthreads();
    if (threadIdx.x < 64) {
        float v = red[threadIdx.x] + red[threadIdx.x + 64] +
                  red[threadIdx.x + 128] + red[threadIdx.x + 192];
        atomicAdd(&h0row[threadIdx.x], v);
    }
}

// ---------------- k=0 logits contribution (n=0, rp=0) ----------------
__global__ __launch_bounds__(64) void k_out0(
    const float* __restrict__ h0row, const float* __restrict__ irs0,
    const float* __restrict__ w2, float* __restrict__ out)
{
    int hq = threadIdx.x >> 4, c = threadIdx.x & 15;
    float v = 0.f;
#pragma unroll
    for (int hh = 0; hh < 16; ++hh) {
        int hd = hq * 16 + hh;
        v = fmaf(h0row[hd], w2[hd * NCLS + c], v);
    }
    v += __shfl_xor(v, 16, 64);
    v += __shfl_xor(v, 32, 64);
    if (threadIdx.x < 16) atomicAdd(&out[c], v * irs0[0]);
}

extern "C" void kernel_launch(void* const* d_in, const int* in_sizes, int n_in,
                              void* d_out, int out_size, void* d_ws, size_t ws_size,
                              hipStream_t stream)
{
    const float* rm    = (const float*)d_in[0];
    const int*   hrow  = (const int*)d_in[1];   // sorted source nodes
    const int*   vcol  = (const int*)d_in[4];   // object nodes
    const float* W1    = (const float*)d_in[5];
    const float* b1    = (const float*)d_in[6];
    const float* W2    = (const float*)d_in[7];
    const float* b2    = (const float*)d_in[8];
    const float* w1    = (const float*)d_in[9];
    const float* w2    = (const float*)d_in[10];
    const float* bias1 = (const float*)d_in[11];
    const float* bias2 = (const float*)d_in[12];
    float* out = (float*)d_out;

    float* ws = (float*)d_ws;
    float*  l1      = ws;                       // [0, 2.00M)
    float*  l2      = ws + 2000000;             // [2.00M, 4.00M)
    int*    rowptr  = (int*)(ws + 4000000);     // 20,001 ints
    float*  h0row   = ws + 4030000;             // 64
    float*  colsum  = ws + 4100000;             // 160,000 (inverted in place)
    float*  rowsum  = ws + 4260000;             // 140,000 (inverted in place)
    __half* h       = (__half*)(ws + 4400000);  // 1.28M halfs [4.40M, 5.04M)
    int*    cnt     = (int*)(ws + 5040000);     // 20,000
    int*    cstart  = cnt + 20000;              // 20,001
    int*    cnt2    = cstart + 20001;           // 20,000
    int*    cscidx  = cnt2 + 20000;             // 250,000 (ends 5.35M)
    __half* contrib = (__half*)(ws + 5600000);  // 16M halfs [5.60M, 13.60M)
    // Abuf0/rs0part overlay l1 (l1 dead after k_contrib)
    float*  Abuf0   = ws;                       // 1.28M
    float*  rs0part = ws + 1280000;             // 20,000

    hipMemsetAsync(colsum, 0, (size_t)160000 * sizeof(float), stream);
    hipMemsetAsync(rowsum, 0, (size_t)KMAX * sizeof(float), stream);
    hipMemsetAsync(h0row, 0, (size_t)64 * sizeof(float), stream);
    hipMemsetAsync(cnt, 0, (size_t)20000 * sizeof(int), stream);

    k_init   <<<RPB + HIB, 256, 0, stream>>>(hrow, rowptr, vcol, cnt);
    k_scan   <<<1, 1024, 0, stream>>>(cnt, cstart, cnt2);
    k_pos    <<<(NT + 255) / 256, 256, 0, stream>>>(vcol, cnt2, cscidx);
    k_gemv   <<<(NT + 255) / 256, 256, 0, stream>>>(rm, W1, b1, W2, b2, l1, l2);
    k_colsum <<<COLB + REDB, 256, 0, stream>>>(l1, cstart, cscidx, colsum);
    k_inv    <<<(RP * NN + 255) / 256, 256, 0, stream>>>(colsum);
    k_contrib<<<(NN * 64) / 256, 256, 0, stream>>>(l1, colsum, cstart, cscidx, w1, contrib);
    k_h      <<<(NN * 64) / 256, 256, 0, stream>>>(contrib, l2, rowptr, bias1, h, rowsum, rs0part);
    k_misc   <<<MISCB + 1, 256, 0, stream>>>(rowsum, out, bias2, rs0part);
    k_l2out  <<<(NN * 64) / 256, 256, 0, stream>>>(l2, rowptr, vcol, h, rowsum, w2, out, Abuf0);
    k_redA   <<<64, 256, 0, stream>>>(Abuf0, h0row);
    k_out0   <<<1, 64, 0, stream>>>(h0row, rowsum, w2, out);
}

// Round 15
// 233.497 us; speedup vs baseline: 1.1538x; 1.0762x over previous
//
#include <hip/hip_runtime.h>
#include <hip/hip_fp16.h>

#define NT      250000
#define NN      20000
#define RP      8
#define EMB     64
#define NCLS    16
#define NRELS   64
#define REDB    64
#define KMAX    140000    // max segment id + 1 (19999*7 = 139993)
#define GEMVB   977       // blocks for gemv part
#define RPB     79        // blocks for rowptr part
#define HIB     977       // blocks for hist part
#define MISCB   1250      // blocks for invert+outinit part

// ---------------- A (fused): LDS-row-tiled GEMV + softmax | rowptr | histogram ----------------
__global__ __launch_bounds__(256) void k_gemv(
    const float* __restrict__ rm,
    const float* __restrict__ W1, const float* __restrict__ b1,
    const float* __restrict__ W2, const float* __restrict__ b2,
    float* __restrict__ l1, float* __restrict__ l2,
    const int* __restrict__ hrow, int* __restrict__ rowptr,
    const int* __restrict__ vcol, int* __restrict__ cnt)
{
    __shared__ float tile[256 * 20];
    int bid = blockIdx.x;
    if (bid >= GEMVB) {
        int b = bid - GEMVB;
        if (b < RPB) {                    // CSR offsets via binary search
            int i = b * 256 + threadIdx.x;
            if (i > NN) return;
            int lo = 0, hi = NT;
            while (lo < hi) { int mid = (lo + hi) >> 1; if (hrow[mid] < i) lo = mid + 1; else hi = mid; }
            rowptr[i] = lo;
        } else {                          // vcol histogram
            int p = (b - RPB) * 256 + threadIdx.x;
            if (p < NT) atomicAdd(&cnt[vcol[p]], 1);
        }
        return;
    }
    int t = threadIdx.x;
    int base = bid * 256;
    float a1[8], a2[8];
#pragma unroll
    for (int r = 0; r < 8; ++r) { a1[r] = b1[r]; a2[r] = b2[r]; }

#pragma unroll 1
    for (int kc = 0; kc < 4; ++kc) {
        __syncthreads();
#pragma unroll
        for (int q = 0; q < 4; ++q) {
            int i = q * 256 + t;
            int pl = i >> 2, j4 = i & 3;
            int p = base + pl;
            float4 v = make_float4(0.f, 0.f, 0.f, 0.f);
            if (p < NT) v = reinterpret_cast<const float4*>(rm)[(size_t)p * 16 + kc * 4 + j4];
            *reinterpret_cast<float4*>(&tile[pl * 20 + j4 * 4]) = v;
        }
        __syncthreads();
        float xr[16];
#pragma unroll
        for (int j4 = 0; j4 < 4; ++j4) {
            float4 v = *reinterpret_cast<const float4*>(&tile[t * 20 + j4 * 4]);
            xr[j4 * 4 + 0] = v.x; xr[j4 * 4 + 1] = v.y;
            xr[j4 * 4 + 2] = v.z; xr[j4 * 4 + 3] = v.w;
        }
#pragma unroll
        for (int kk = 0; kk < 16; ++kk) {
            float x = xr[kk];
            int k = kc * 16 + kk;
#pragma unroll
            for (int r = 0; r < 8; ++r) {
                a1[r] = fmaf(x, W1[k * 8 + r], a1[r]);
                a2[r] = fmaf(x, W2[k * 8 + r], a2[r]);
            }
        }
    }
    int p = base + t;
    if (p >= NT) return;
    float mx = a2[0];
#pragma unroll
    for (int r = 1; r < 8; ++r) mx = fmaxf(mx, a2[r]);
    float sm = 0.f;
#pragma unroll
    for (int r = 0; r < 8; ++r) { a2[r] = __expf(a2[r] - mx); sm += a2[r]; }
    float inv = 1.0f / sm;
#pragma unroll
    for (int r = 0; r < 8; ++r) a2[r] *= inv;
    float4* o1 = reinterpret_cast<float4*>(l1 + (size_t)p * 8);
    float4* o2 = reinterpret_cast<float4*>(l2 + (size_t)p * 8);
    o1[0] = make_float4(a1[0], a1[1], a1[2], a1[3]);
    o1[1] = make_float4(a1[4], a1[5], a1[6], a1[7]);
    o2[0] = make_float4(a2[0], a2[1], a2[2], a2[3]);
    o2[1] = make_float4(a2[4], a2[5], a2[6], a2[7]);
}

__global__ __launch_bounds__(1024) void k_scan(
    const int* __restrict__ cnt, int* __restrict__ cstart, int* __restrict__ cnt2)
{
    __shared__ int part[1024];
    int t = threadIdx.x;
    int base = t * 20;
    int local[20];
    int s = 0;
#pragma unroll
    for (int i = 0; i < 20; ++i) {
        int idx = base + i;
        int c = (idx < NN) ? cnt[idx] : 0;
        local[i] = s;
        s += c;
    }
    part[t] = s;
    __syncthreads();
    for (int off = 1; off < 1024; off <<= 1) {
        int v = (t >= off) ? part[t - off] : 0;
        __syncthreads();
        part[t] += v;
        __syncthreads();
    }
    int ebase = t ? part[t - 1] : 0;
#pragma unroll
    for (int i = 0; i < 20; ++i) {
        int idx = base + i;
        if (idx < NN) { cstart[idx] = ebase + local[i]; cnt2[idx] = ebase + local[i]; }
    }
    if (t == 1023) cstart[NN] = part[1023];
}

__global__ __launch_bounds__(256) void k_pos(
    const int* __restrict__ vcol, int* __restrict__ cnt2, int* __restrict__ cscidx)
{
    int p = blockIdx.x * blockDim.x + threadIdx.x;
    if (p >= NT) return;
    int o = vcol[p];
    int slot = atomicAdd(&cnt2[o], 1);
    cscidx[slot] = p;
}

// ---------------- colsum: wave per o (r=1..7), 8x32B row gathers + shfl reduce;
// r=0 column handled by REDB streaming reducer blocks -> colsum[0] ----------------
__global__ __launch_bounds__(256) void k_colsum(
    const float* __restrict__ l1, const int* __restrict__ cstart,
    const int* __restrict__ cscidx, float* __restrict__ colsum)
{
    int bid = blockIdx.x;
    if (bid < NN / 4) {
        int o = bid * 4 + (threadIdx.x >> 6);
        int lane = threadIdx.x & 63;
        int qb = cstart[o], qe = cstart[o + 1];
        if (qb == qe) return;
        int j = lane >> 3, r = lane & 7;
        float sum = 0.f;
        for (int q0 = qb; q0 < qe; q0 += 8) {
            int q = q0 + j;
            if (q < qe) sum += l1[(size_t)cscidx[q] * 8 + r];
        }
        sum += __shfl_xor(sum, 8, 64);
        sum += __shfl_xor(sum, 16, 64);
        sum += __shfl_xor(sum, 32, 64);   // lanes 0..7 hold per-r totals
        if (lane >= 1 && lane < 8) atomicAdd(&colsum[o * lane], sum);  // o=0 -> colsum[0], correct
    } else {
        int b2 = bid - NN / 4;
        float s = 0.f;
        for (int i = b2 * 256 + threadIdx.x; i < NT; i += REDB * 256) s += l1[(size_t)i * 8];
        __shared__ float red[256];
        red[threadIdx.x] = s;
        __syncthreads();
        for (int off = 128; off > 0; off >>= 1) {
            if (threadIdx.x < off) red[threadIdx.x] += red[threadIdx.x + off];
            __syncthreads();
        }
        if (threadIdx.x == 0) atomicAdd(&colsum[0], red[0]);
    }
}

// ---------------- C1: per-object contributions (division folded; unroll-2 gathers) ----------------
__global__ __launch_bounds__(256) void k_contrib(
    const float* __restrict__ l1, const float* __restrict__ colsum,
    const int* __restrict__ cstart, const int* __restrict__ cscidx,
    const float* __restrict__ w1, __half* __restrict__ contrib)
{
    int o = (int)((blockIdx.x * blockDim.x + threadIdx.x) >> 6);
    int lane = threadIdx.x & 63;
    if (o >= NN) return;
    int qb = cstart[o], qe = cstart[o + 1];
    if (qb == qe) return;
    float y[8];
    y[0] = w1[lane] / colsum[0];
#pragma unroll
    for (int r = 1; r < 8; ++r) {
        int seg = o * r;
        y[r] = w1[(size_t)seg * EMB + lane] / colsum[seg];
    }
    int q = qb;
    for (; q + 1 < qe; q += 2) {          // two l1 gathers in flight
        int p0 = cscidx[q], p1 = cscidx[q + 1];
        const float4* a4 = reinterpret_cast<const float4*>(l1 + (size_t)p0 * 8);
        const float4* b4 = reinterpret_cast<const float4*>(l1 + (size_t)p1 * 8);
        float4 A = a4[0], B = a4[1], C = b4[0], D = b4[1];
        float v0 = A.x * y[0];
        v0 = fmaf(A.y, y[1], v0); v0 = fmaf(A.z, y[2], v0); v0 = fmaf(A.w, y[3], v0);
        v0 = fmaf(B.x, y[4], v0); v0 = fmaf(B.y, y[5], v0);
        v0 = fmaf(B.z, y[6], v0); v0 = fmaf(B.w, y[7], v0);
        float v1 = C.x * y[0];
        v1 = fmaf(C.y, y[1], v1); v1 = fmaf(C.z, y[2], v1); v1 = fmaf(C.w, y[3], v1);
        v1 = fmaf(D.x, y[4], v1); v1 = fmaf(D.y, y[5], v1);
        v1 = fmaf(D.z, y[6], v1); v1 = fmaf(D.w, y[7], v1);
        contrib[(size_t)p0 * EMB + lane] = __float2half(v0);
        contrib[(size_t)p1 * EMB + lane] = __float2half(v1);
    }
    if (q < qe) {
        int p0 = cscidx[q];
        const float4* a4 = reinterpret_cast<const float4*>(l1 + (size_t)p0 * 8);
        float4 A = a4[0], B = a4[1];
        float v0 = A.x * y[0];
        v0 = fmaf(A.y, y[1], v0); v0 = fmaf(A.z, y[2], v0); v0 = fmaf(A.w, y[3], v0);
        v0 = fmaf(B.x, y[4], v0); v0 = fmaf(B.y, y[5], v0);
        v0 = fmaf(B.z, y[6], v0); v0 = fmaf(B.w, y[7], v0);
        contrib[(size_t)p0 * EMB + lane] = __float2half(v0);
    }
}

// ---------------- C2 (fused): h = relu(bias + sum contrib) + rowsum pre-pass ----------------
__global__ __launch_bounds__(256) void k_h(
    const __half* __restrict__ contrib, const float* __restrict__ l2,
    const int* __restrict__ rowptr, const float* __restrict__ bias1,
    __half* __restrict__ h, float* __restrict__ rowsum, float* __restrict__ rs0part)
{
    int s = (int)((blockIdx.x * blockDim.x + threadIdx.x) >> 6);
    int lane = threadIdx.x & 63;
    if (s >= NN) return;
    int pb = rowptr[s], pe = rowptr[s + 1];
    float acc = 0.f;
    for (int p = pb; p < pe; ++p)
        acc += __half2float(contrib[(size_t)p * EMB + lane]);
    h[(size_t)s * EMB + lane] = __float2half(fmaxf(acc + bias1[lane], 0.f));

    float psum = 0.f;
    for (int p0 = pb + (lane >> 3); p0 < pe; p0 += 8)
        psum += l2[(size_t)p0 * 8 + (lane & 7)];
    psum += __shfl_xor(psum, 8, 64);
    psum += __shfl_xor(psum, 16, 64);
    psum += __shfl_xor(psum, 32, 64);
    if (s == 0) {
        float tt = psum;
        tt += __shfl_xor(tt, 1, 64);
        tt += __shfl_xor(tt, 2, 64);
        tt += __shfl_xor(tt, 4, 64);
        if (lane == 0) rs0part[0] = tt;
    } else {
        if (lane == 0) rs0part[s] = psum;
        else if (lane < 8) atomicAdd(&rowsum[s * lane], psum);
    }
}

// ---------------- fused: rowsum inversion + out=bias2 init + rs0 reduce ----------------
__global__ __launch_bounds__(256) void k_misc(
    float* __restrict__ rs, float* __restrict__ out, const float* __restrict__ b2,
    const float* __restrict__ rs0part)
{
    int bid = blockIdx.x;
    if (bid < MISCB) {
        int i = bid * 256 + threadIdx.x;
        if (i >= 1 && i < KMAX) rs[i] = 1.0f / fmaxf(rs[i], 1e-6f);
        if (i < NN * NCLS) out[i] = b2[i & (NCLS - 1)];
    } else {
        __shared__ float red[256];
        float sv = 0.f;
        for (int i = threadIdx.x; i < NN; i += 256) sv += rs0part[i];
        red[threadIdx.x] = sv;
        __syncthreads();
        for (int off = 128; off > 0; off >>= 1) {
            if (threadIdx.x < off) red[threadIdx.x] += red[threadIdx.x + off];
            __syncthreads();
        }
        if (threadIdx.x == 0) rs[0] = 1.0f / fmaxf(red[0], 1e-6f);
    }
}

// ---------------- D+E fused: single wave per s, unroll-4, hoisted irs (frozen) ----------------
__global__ __launch_bounds__(256) void k_l2out(
    const float* __restrict__ l2, const int* __restrict__ rowptr,
    const int* __restrict__ vcol, const __half* __restrict__ h,
    const float* __restrict__ irs, const float* __restrict__ w2,
    float* __restrict__ out, float* __restrict__ Abuf0)
{
    int s = (int)((blockIdx.x * blockDim.x + threadIdx.x) >> 6);
    int lane = threadIdx.x & 63;
    if (s >= NN) return;
    int pb = rowptr[s], pe = rowptr[s + 1];
    float sc[8];
#pragma unroll
    for (int rr = 1; rr < 8; ++rr) sc[rr] = (s > 0) ? irs[s * rr] : 0.f;
    float acc[8];
#pragma unroll
    for (int r = 0; r < 8; ++r) acc[r] = 0.f;
    int p = pb;
    for (; p + 3 < pe; p += 4) {            // four h gathers in flight
        int o0 = vcol[p], o1 = vcol[p + 1], o2 = vcol[p + 2], o3 = vcol[p + 3];
        float hv0 = __half2float(h[(size_t)o0 * EMB + lane]);
        float hv1 = __half2float(h[(size_t)o1 * EMB + lane]);
        float hv2 = __half2float(h[(size_t)o2 * EMB + lane]);
        float hv3 = __half2float(h[(size_t)o3 * EMB + lane]);
        const float4* q4 = reinterpret_cast<const float4*>(l2 + (size_t)p * 8);
        float4 A = q4[0], B = q4[1], C = q4[2], D = q4[3];
        float4 E = q4[4], F = q4[5], G = q4[6], H = q4[7];
        acc[0] = fmaf(A.x, hv0, fmaf(C.x, hv1, fmaf(E.x, hv2, fmaf(G.x, hv3, acc[0]))));
        acc[1] = fmaf(A.y, hv0, fmaf(C.y, hv1, fmaf(E.y, hv2, fmaf(G.y, hv3, acc[1]))));
        acc[2] = fmaf(A.z, hv0, fmaf(C.z, hv1, fmaf(E.z, hv2, fmaf(G.z, hv3, acc[2]))));
        acc[3] = fmaf(A.w, hv0, fmaf(C.w, hv1, fmaf(E.w, hv2, fmaf(G.w, hv3, acc[3]))));
        acc[4] = fmaf(B.x, hv0, fmaf(D.x, hv1, fmaf(F.x, hv2, fmaf(H.x, hv3, acc[4]))));
        acc[5] = fmaf(B.y, hv0, fmaf(D.y, hv1, fmaf(F.y, hv2, fmaf(H.y, hv3, acc[5]))));
        acc[6] = fmaf(B.z, hv0, fmaf(D.z, hv1, fmaf(F.z, hv2, fmaf(H.z, hv3, acc[6]))));
        acc[7] = fmaf(B.w, hv0, fmaf(D.w, hv1, fmaf(F.w, hv2, fmaf(H.w, hv3, acc[7]))));
    }
    for (; p < pe; ++p) {
        int o0 = vcol[p];
        float hv0 = __half2float(h[(size_t)o0 * EMB + lane]);
        const float4* q4 = reinterpret_cast<const float4*>(l2 + (size_t)p * 8);
        float4 A = q4[0], B = q4[1];
        acc[0] = fmaf(A.x, hv0, acc[0]); acc[1] = fmaf(A.y, hv0, acc[1]);
        acc[2] = fmaf(A.z, hv0, acc[2]); acc[3] = fmaf(A.w, hv0, acc[3]);
        acc[4] = fmaf(B.x, hv0, acc[4]); acc[5] = fmaf(B.y, hv0, acc[5]);
        acc[6] = fmaf(B.z, hv0, acc[6]); acc[7] = fmaf(B.w, hv0, acc[7]);
    }
    if (s == 0) {
        float a = acc[0] + acc[1] + acc[2] + acc[3] +
                  acc[4] + acc[5] + acc[6] + acc[7];
        Abuf0[lane] = a;
        return;
    }
    Abuf0[(size_t)s * EMB + lane] = acc[0];
    if (pb == pe) return;
    int hq = lane >> 4, c = lane & 15;
#pragma unroll
    for (int rr = 1; rr < 8; ++rr) {
        int k = s * rr;
        int rp = k / NN;
        int n  = k - rp * NN;
        float v = 0.f;
#pragma unroll
        for (int hh = 0; hh < 16; ++hh) {
            float av = __shfl(acc[rr], hq * 16 + hh, 64);
            v = fmaf(av, w2[((rp * EMB) + (hq * 16 + hh)) * NCLS + c], v);
        }
        v += __shfl_xor(v, 16, 64);
        v += __shfl_xor(v, 32, 64);
        if (lane < 16) atomicAdd(&out[(size_t)n * NCLS + lane], v * sc[rr]);
    }
}

// ---------------- reduce Abuf0 -> partial h0 row + folded k=0 logits dot ----------------
__global__ __launch_bounds__(256) void k_redA(
    const float* __restrict__ Abuf0, const float* __restrict__ irs,
    const float* __restrict__ w2, float* __restrict__ out)
{
    __shared__ float red[256];
    __shared__ float part[64];
    int lane = threadIdx.x & 63, w = threadIdx.x >> 6;
    float sum = 0.f;
    for (int ss = blockIdx.x + 64 * w; ss < NN; ss += 256)
        sum += Abuf0[(size_t)ss * EMB + lane];
    red[threadIdx.x] = sum;
    __syncthreads();
    if (threadIdx.x < 64) {
        part[threadIdx.x] = red[threadIdx.x] + red[threadIdx.x + 64] +
                            red[threadIdx.x + 128] + red[threadIdx.x + 192];
    }
    __syncthreads();
    if (threadIdx.x < 64) {
        int hq = threadIdx.x >> 4, c = threadIdx.x & 15;
        float v = 0.f;
#pragma unroll
        for (int hh = 0; hh < 16; ++hh) {
            int hd = hq * 16 + hh;
            v = fmaf(part[hd], w2[hd * NCLS + c], v);
        }
        v += __shfl_xor(v, 16, 64);
        v += __shfl_xor(v, 32, 64);
        if (threadIdx.x < 16) atomicAdd(&out[c], v * irs[0]);
    }
}

extern "C" void kernel_launch(void* const* d_in, const int* in_sizes, int n_in,
                              void* d_out, int out_size, void* d_ws, size_t ws_size,
                              hipStream_t stream)
{
    const float* rm    = (const float*)d_in[0];
    const int*   hrow  = (const int*)d_in[1];   // sorted source nodes
    const int*   vcol  = (const int*)d_in[4];   // object nodes
    const float* W1    = (const float*)d_in[5];
    const float* b1    = (const float*)d_in[6];
    const float* W2    = (const float*)d_in[7];
    const float* b2    = (const float*)d_in[8];
    const float* w1    = (const float*)d_in[9];
    const float* w2    = (const float*)d_in[10];
    const float* bias1 = (const float*)d_in[11];
    const float* bias2 = (const float*)d_in[12];
    float* out = (float*)d_out;

    float* ws = (float*)d_ws;
    float*  l1      = ws;                       // [0, 2.00M)
    float*  l2      = ws + 2000000;             // [2.00M, 4.00M)
    int*    rowptr  = (int*)(ws + 4000000);     // 20,001 ints
    float*  colsum  = ws + 4100000;             // 160,000 (raw; divided in k_contrib)
    float*  rowsum  = ws + 4260000;             // 140,000 (inverted in place by k_misc)
    __half* h       = (__half*)(ws + 4400000);  // 1.28M halfs [4.40M, 5.04M)
    int*    cnt     = (int*)(ws + 5040000);     // 20,000
    int*    cstart  = cnt + 20000;              // 20,001
    int*    cnt2    = cstart + 20001;           // 20,000
    int*    cscidx  = cnt2 + 20000;             // 250,000 (ends 5.35M)
    __half* contrib = (__half*)(ws + 5600000);  // 16M halfs [5.60M, 13.60M)
    // Abuf0/rs0part overlay l1 (l1 dead after k_contrib)
    float*  Abuf0   = ws;                       // 1.28M
    float*  rs0part = ws + 1280000;             // 20,000

    hipMemsetAsync(colsum, 0, (size_t)160000 * sizeof(float), stream);
    hipMemsetAsync(rowsum, 0, (size_t)KMAX * sizeof(float), stream);
    hipMemsetAsync(cnt, 0, (size_t)20000 * sizeof(int), stream);

    k_gemv   <<<GEMVB + RPB + HIB, 256, 0, stream>>>(rm, W1, b1, W2, b2, l1, l2,
                                                     hrow, rowptr, vcol, cnt);
    k_scan   <<<1, 1024, 0, stream>>>(cnt, cstart, cnt2);
    k_pos    <<<(NT + 255) / 256, 256, 0, stream>>>(vcol, cnt2, cscidx);
    k_colsum <<<NN / 4 + REDB, 256, 0, stream>>>(l1, cstart, cscidx, colsum);
    k_contrib<<<(NN * 64) / 256, 256, 0, stream>>>(l1, colsum, cstart, cscidx, w1, contrib);
    k_h      <<<(NN * 64) / 256, 256, 0, stream>>>(contrib, l2, rowptr, bias1, h, rowsum, rs0part);
    k_misc   <<<MISCB + 1, 256, 0, stream>>>(rowsum, out, bias2, rs0part);
    k_l2out  <<<(NN * 64) / 256, 256, 0, stream>>>(l2, rowptr, vcol, h, rowsum, w2, out, Abuf0);
    k_redA   <<<64, 256, 0, stream>>>(Abuf0, rowsum, w2, out);
}

// Round 16
// 233.216 us; speedup vs baseline: 1.1552x; 1.0012x over previous
//
#include <hip/hip_runtime.h>
#include <hip/hip_fp16.h>

#define NT      250000
#define NN      20000
#define RP      8
#define EMB     64
#define NCLS    16
#define NRELS   64
#define REDB    64
#define KMAX    140000    // max segment id + 1 (19999*7 = 139993)
#define GEMVB   977       // blocks for gemv part
#define RPB     79        // blocks for rowptr part
#define HIB     977       // blocks for hist part
#define OIB     1250      // blocks for out=bias2 init part (1250*256 = 320000 exactly)

// ---------------- A (fused): GEMV + softmax | rowptr | histogram | out-init ----------------
__global__ __launch_bounds__(256) void k_gemv(
    const float* __restrict__ rm,
    const float* __restrict__ W1, const float* __restrict__ b1,
    const float* __restrict__ W2, const float* __restrict__ b2,
    float* __restrict__ l1, float* __restrict__ l2,
    const int* __restrict__ hrow, int* __restrict__ rowptr,
    const int* __restrict__ vcol, int* __restrict__ cnt,
    float* __restrict__ out, const float* __restrict__ bias2)
{
    __shared__ float tile[256 * 20];
    int bid = blockIdx.x;
    if (bid >= GEMVB) {
        int b = bid - GEMVB;
        if (b < RPB) {                    // CSR offsets via binary search
            int i = b * 256 + threadIdx.x;
            if (i > NN) return;
            int lo = 0, hi = NT;
            while (lo < hi) { int mid = (lo + hi) >> 1; if (hrow[mid] < i) lo = mid + 1; else hi = mid; }
            rowptr[i] = lo;
        } else if (b < RPB + HIB) {       // vcol histogram
            int p = (b - RPB) * 256 + threadIdx.x;
            if (p < NT) atomicAdd(&cnt[vcol[p]], 1);
        } else {                          // out = bias2 broadcast
            int i = (b - RPB - HIB) * 256 + threadIdx.x;
            if (i < NN * NCLS) out[i] = bias2[i & (NCLS - 1)];
        }
        return;
    }
    int t = threadIdx.x;
    int base = bid * 256;
    float a1[8], a2[8];
#pragma unroll
    for (int r = 0; r < 8; ++r) { a1[r] = b1[r]; a2[r] = b2[r]; }

#pragma unroll 1
    for (int kc = 0; kc < 4; ++kc) {
        __syncthreads();
#pragma unroll
        for (int q = 0; q < 4; ++q) {
            int i = q * 256 + t;
            int pl = i >> 2, j4 = i & 3;
            int p = base + pl;
            float4 v = make_float4(0.f, 0.f, 0.f, 0.f);
            if (p < NT) v = reinterpret_cast<const float4*>(rm)[(size_t)p * 16 + kc * 4 + j4];
            *reinterpret_cast<float4*>(&tile[pl * 20 + j4 * 4]) = v;
        }
        __syncthreads();
        float xr[16];
#pragma unroll
        for (int j4 = 0; j4 < 4; ++j4) {
            float4 v = *reinterpret_cast<const float4*>(&tile[t * 20 + j4 * 4]);
            xr[j4 * 4 + 0] = v.x; xr[j4 * 4 + 1] = v.y;
            xr[j4 * 4 + 2] = v.z; xr[j4 * 4 + 3] = v.w;
        }
#pragma unroll
        for (int kk = 0; kk < 16; ++kk) {
            float x = xr[kk];
            int k = kc * 16 + kk;
#pragma unroll
            for (int r = 0; r < 8; ++r) {
                a1[r] = fmaf(x, W1[k * 8 + r], a1[r]);
                a2[r] = fmaf(x, W2[k * 8 + r], a2[r]);
            }
        }
    }
    int p = base + t;
    if (p >= NT) return;
    float mx = a2[0];
#pragma unroll
    for (int r = 1; r < 8; ++r) mx = fmaxf(mx, a2[r]);
    float sm = 0.f;
#pragma unroll
    for (int r = 0; r < 8; ++r) { a2[r] = __expf(a2[r] - mx); sm += a2[r]; }
    float inv = 1.0f / sm;
#pragma unroll
    for (int r = 0; r < 8; ++r) a2[r] *= inv;
    float4* o1 = reinterpret_cast<float4*>(l1 + (size_t)p * 8);
    float4* o2 = reinterpret_cast<float4*>(l2 + (size_t)p * 8);
    o1[0] = make_float4(a1[0], a1[1], a1[2], a1[3]);
    o1[1] = make_float4(a1[4], a1[5], a1[6], a1[7]);
    o2[0] = make_float4(a2[0], a2[1], a2[2], a2[3]);
    o2[1] = make_float4(a2[4], a2[5], a2[6], a2[7]);
}

__global__ __launch_bounds__(1024) void k_scan(
    const int* __restrict__ cnt, int* __restrict__ cstart, int* __restrict__ cnt2)
{
    __shared__ int part[1024];
    int t = threadIdx.x;
    int base = t * 20;
    int local[20];
    int s = 0;
#pragma unroll
    for (int i = 0; i < 20; ++i) {
        int idx = base + i;
        int c = (idx < NN) ? cnt[idx] : 0;
        local[i] = s;
        s += c;
    }
    part[t] = s;
    __syncthreads();
    for (int off = 1; off < 1024; off <<= 1) {
        int v = (t >= off) ? part[t - off] : 0;
        __syncthreads();
        part[t] += v;
        __syncthreads();
    }
    int ebase = t ? part[t - 1] : 0;
#pragma unroll
    for (int i = 0; i < 20; ++i) {
        int idx = base + i;
        if (idx < NN) { cstart[idx] = ebase + local[i]; cnt2[idx] = ebase + local[i]; }
    }
    if (t == 1023) cstart[NN] = part[1023];
}

__global__ __launch_bounds__(256) void k_pos(
    const int* __restrict__ vcol, int* __restrict__ cnt2, int* __restrict__ cscidx)
{
    int p = blockIdx.x * blockDim.x + threadIdx.x;
    if (p >= NT) return;
    int o = vcol[p];
    int slot = atomicAdd(&cnt2[o], 1);
    cscidx[slot] = p;
}

// ---------------- colsum: wave per o (r=1..7) + REDB streaming blocks (r=0 -> colsum[0]) ----------------
__global__ __launch_bounds__(256) void k_colsum(
    const float* __restrict__ l1, const int* __restrict__ cstart,
    const int* __restrict__ cscidx, float* __restrict__ colsum)
{
    int bid = blockIdx.x;
    if (bid < NN / 4) {
        int o = bid * 4 + (threadIdx.x >> 6);
        int lane = threadIdx.x & 63;
        int qb = cstart[o], qe = cstart[o + 1];
        if (qb == qe) return;
        int j = lane >> 3, r = lane & 7;
        float sum = 0.f;
        for (int q0 = qb; q0 < qe; q0 += 8) {
            int q = q0 + j;
            if (q < qe) sum += l1[(size_t)cscidx[q] * 8 + r];
        }
        sum += __shfl_xor(sum, 8, 64);
        sum += __shfl_xor(sum, 16, 64);
        sum += __shfl_xor(sum, 32, 64);   // lanes 0..7 hold per-r totals
        if (lane >= 1 && lane < 8) atomicAdd(&colsum[o * lane], sum);
    } else {
        int b2 = bid - NN / 4;
        float s = 0.f;
        for (int i = b2 * 256 + threadIdx.x; i < NT; i += REDB * 256) s += l1[(size_t)i * 8];
        __shared__ float red[256];
        red[threadIdx.x] = s;
        __syncthreads();
        for (int off = 128; off > 0; off >>= 1) {
            if (threadIdx.x < off) red[threadIdx.x] += red[threadIdx.x + off];
            __syncthreads();
        }
        if (threadIdx.x == 0) atomicAdd(&colsum[0], red[0]);
    }
}

// ---------------- C1: per-object contributions (division folded; unroll-4 gathers) ----------------
__global__ __launch_bounds__(256) void k_contrib(
    const float* __restrict__ l1, const float* __restrict__ colsum,
    const int* __restrict__ cstart, const int* __restrict__ cscidx,
    const float* __restrict__ w1, __half* __restrict__ contrib)
{
    int o = (int)((blockIdx.x * blockDim.x + threadIdx.x) >> 6);
    int lane = threadIdx.x & 63;
    if (o >= NN) return;
    int qb = cstart[o], qe = cstart[o + 1];
    if (qb == qe) return;
    float y[8];
    y[0] = w1[lane] / colsum[0];
#pragma unroll
    for (int r = 1; r < 8; ++r) {
        int seg = o * r;
        y[r] = w1[(size_t)seg * EMB + lane] / colsum[seg];
    }
    int q = qb;
    for (; q + 3 < qe; q += 4) {          // four l1 gathers in flight
        int p0 = cscidx[q], p1 = cscidx[q + 1], p2 = cscidx[q + 2], p3 = cscidx[q + 3];
        const float4* a4 = reinterpret_cast<const float4*>(l1 + (size_t)p0 * 8);
        const float4* b4 = reinterpret_cast<const float4*>(l1 + (size_t)p1 * 8);
        const float4* c4 = reinterpret_cast<const float4*>(l1 + (size_t)p2 * 8);
        const float4* d4 = reinterpret_cast<const float4*>(l1 + (size_t)p3 * 8);
        float4 A = a4[0], B = a4[1], C = b4[0], D = b4[1];
        float4 E = c4[0], F = c4[1], G = d4[0], H = d4[1];
        float v0 = A.x * y[0];
        v0 = fmaf(A.y, y[1], v0); v0 = fmaf(A.z, y[2], v0); v0 = fmaf(A.w, y[3], v0);
        v0 = fmaf(B.x, y[4], v0); v0 = fmaf(B.y, y[5], v0);
        v0 = fmaf(B.z, y[6], v0); v0 = fmaf(B.w, y[7], v0);
        float v1 = C.x * y[0];
        v1 = fmaf(C.y, y[1], v1); v1 = fmaf(C.z, y[2], v1); v1 = fmaf(C.w, y[3], v1);
        v1 = fmaf(D.x, y[4], v1); v1 = fmaf(D.y, y[5], v1);
        v1 = fmaf(D.z, y[6], v1); v1 = fmaf(D.w, y[7], v1);
        float v2 = E.x * y[0];
        v2 = fmaf(E.y, y[1], v2); v2 = fmaf(E.z, y[2], v2); v2 = fmaf(E.w, y[3], v2);
        v2 = fmaf(F.x, y[4], v2); v2 = fmaf(F.y, y[5], v2);
        v2 = fmaf(F.z, y[6], v2); v2 = fmaf(F.w, y[7], v2);
        float v3 = G.x * y[0];
        v3 = fmaf(G.y, y[1], v3); v3 = fmaf(G.z, y[2], v3); v3 = fmaf(G.w, y[3], v3);
        v3 = fmaf(H.x, y[4], v3); v3 = fmaf(H.y, y[5], v3);
        v3 = fmaf(H.z, y[6], v3); v3 = fmaf(H.w, y[7], v3);
        contrib[(size_t)p0 * EMB + lane] = __float2half(v0);
        contrib[(size_t)p1 * EMB + lane] = __float2half(v1);
        contrib[(size_t)p2 * EMB + lane] = __float2half(v2);
        contrib[(size_t)p3 * EMB + lane] = __float2half(v3);
    }
    for (; q < qe; ++q) {
        int p0 = cscidx[q];
        const float4* a4 = reinterpret_cast<const float4*>(l1 + (size_t)p0 * 8);
        float4 A = a4[0], B = a4[1];
        float v0 = A.x * y[0];
        v0 = fmaf(A.y, y[1], v0); v0 = fmaf(A.z, y[2], v0); v0 = fmaf(A.w, y[3], v0);
        v0 = fmaf(B.x, y[4], v0); v0 = fmaf(B.y, y[5], v0);
        v0 = fmaf(B.z, y[6], v0); v0 = fmaf(B.w, y[7], v0);
        contrib[(size_t)p0 * EMB + lane] = __float2half(v0);
    }
}

// ---------------- C2 (fused): h = relu(bias + sum contrib) + rowsum pre-pass ----------------
__global__ __launch_bounds__(256) void k_h(
    const __half* __restrict__ contrib, const float* __restrict__ l2,
    const int* __restrict__ rowptr, const float* __restrict__ bias1,
    __half* __restrict__ h, float* __restrict__ rowsum, float* __restrict__ rs0part)
{
    int s = (int)((blockIdx.x * blockDim.x + threadIdx.x) >> 6);
    int lane = threadIdx.x & 63;
    if (s >= NN) return;
    int pb = rowptr[s], pe = rowptr[s + 1];
    float acc = 0.f;
    for (int p = pb; p < pe; ++p)
        acc += __half2float(contrib[(size_t)p * EMB + lane]);
    h[(size_t)s * EMB + lane] = __float2half(fmaxf(acc + bias1[lane], 0.f));

    float psum = 0.f;
    for (int p0 = pb + (lane >> 3); p0 < pe; p0 += 8)
        psum += l2[(size_t)p0 * 8 + (lane & 7)];
    psum += __shfl_xor(psum, 8, 64);
    psum += __shfl_xor(psum, 16, 64);
    psum += __shfl_xor(psum, 32, 64);
    if (s == 0) {
        float tt = psum;
        tt += __shfl_xor(tt, 1, 64);
        tt += __shfl_xor(tt, 2, 64);
        tt += __shfl_xor(tt, 4, 64);
        if (lane == 0) rs0part[0] = tt;
    } else {
        if (lane == 0) rs0part[s] = psum;
        else if (lane < 8) atomicAdd(&rowsum[s * lane], psum);
    }
}

// ---------------- D+E fused: single wave per s, unroll-4, inline rowsum divides ----------------
__global__ __launch_bounds__(256) void k_l2out(
    const float* __restrict__ l2, const int* __restrict__ rowptr,
    const int* __restrict__ vcol, const __half* __restrict__ h,
    const float* __restrict__ rowsum, const float* __restrict__ w2,
    float* __restrict__ out, float* __restrict__ Abuf0)
{
    int s = (int)((blockIdx.x * blockDim.x + threadIdx.x) >> 6);
    int lane = threadIdx.x & 63;
    if (s >= NN) return;
    int pb = rowptr[s], pe = rowptr[s + 1];
    float sc[8];
#pragma unroll
    for (int rr = 1; rr < 8; ++rr)
        sc[rr] = (s > 0) ? (1.0f / fmaxf(rowsum[s * rr], 1e-6f)) : 0.f;
    float acc[8];
#pragma unroll
    for (int r = 0; r < 8; ++r) acc[r] = 0.f;
    int p = pb;
    for (; p + 3 < pe; p += 4) {            // four h gathers in flight
        int o0 = vcol[p], o1 = vcol[p + 1], o2 = vcol[p + 2], o3 = vcol[p + 3];
        float hv0 = __half2float(h[(size_t)o0 * EMB + lane]);
        float hv1 = __half2float(h[(size_t)o1 * EMB + lane]);
        float hv2 = __half2float(h[(size_t)o2 * EMB + lane]);
        float hv3 = __half2float(h[(size_t)o3 * EMB + lane]);
        const float4* q4 = reinterpret_cast<const float4*>(l2 + (size_t)p * 8);
        float4 A = q4[0], B = q4[1], C = q4[2], D = q4[3];
        float4 E = q4[4], F = q4[5], G = q4[6], H = q4[7];
        acc[0] = fmaf(A.x, hv0, fmaf(C.x, hv1, fmaf(E.x, hv2, fmaf(G.x, hv3, acc[0]))));
        acc[1] = fmaf(A.y, hv0, fmaf(C.y, hv1, fmaf(E.y, hv2, fmaf(G.y, hv3, acc[1]))));
        acc[2] = fmaf(A.z, hv0, fmaf(C.z, hv1, fmaf(E.z, hv2, fmaf(G.z, hv3, acc[2]))));
        acc[3] = fmaf(A.w, hv0, fmaf(C.w, hv1, fmaf(E.w, hv2, fmaf(G.w, hv3, acc[3]))));
        acc[4] = fmaf(B.x, hv0, fmaf(D.x, hv1, fmaf(F.x, hv2, fmaf(H.x, hv3, acc[4]))));
        acc[5] = fmaf(B.y, hv0, fmaf(D.y, hv1, fmaf(F.y, hv2, fmaf(H.y, hv3, acc[5]))));
        acc[6] = fmaf(B.z, hv0, fmaf(D.z, hv1, fmaf(F.z, hv2, fmaf(H.z, hv3, acc[6]))));
        acc[7] = fmaf(B.w, hv0, fmaf(D.w, hv1, fmaf(F.w, hv2, fmaf(H.w, hv3, acc[7]))));
    }
    for (; p < pe; ++p) {
        int o0 = vcol[p];
        float hv0 = __half2float(h[(size_t)o0 * EMB + lane]);
        const float4* q4 = reinterpret_cast<const float4*>(l2 + (size_t)p * 8);
        float4 A = q4[0], B = q4[1];
        acc[0] = fmaf(A.x, hv0, acc[0]); acc[1] = fmaf(A.y, hv0, acc[1]);
        acc[2] = fmaf(A.z, hv0, acc[2]); acc[3] = fmaf(A.w, hv0, acc[3]);
        acc[4] = fmaf(B.x, hv0, acc[4]); acc[5] = fmaf(B.y, hv0, acc[5]);
        acc[6] = fmaf(B.z, hv0, acc[6]); acc[7] = fmaf(B.w, hv0, acc[7]);
    }
    if (s == 0) {
        float a = acc[0] + acc[1] + acc[2] + acc[3] +
                  acc[4] + acc[5] + acc[6] + acc[7];
        Abuf0[lane] = a;
        return;
    }
    Abuf0[(size_t)s * EMB + lane] = acc[0];
    if (pb == pe) return;
    int hq = lane >> 4, c = lane & 15;
#pragma unroll
    for (int rr = 1; rr < 8; ++rr) {
        int k = s * rr;
        int rp = k / NN;
        int n  = k - rp * NN;
        float v = 0.f;
#pragma unroll
        for (int hh = 0; hh < 16; ++hh) {
            float av = __shfl(acc[rr], hq * 16 + hh, 64);
            v = fmaf(av, w2[((rp * EMB) + (hq * 16 + hh)) * NCLS + c], v);
        }
        v += __shfl_xor(v, 16, 64);
        v += __shfl_xor(v, 32, 64);
        if (lane < 16) atomicAdd(&out[(size_t)n * NCLS + lane], v * sc[rr]);
    }
}

// ---------------- reduce Abuf0 + rs0part -> k=0 logits contribution ----------------
__global__ __launch_bounds__(256) void k_redA(
    const float* __restrict__ Abuf0, const float* __restrict__ rs0part,
    const float* __restrict__ w2, float* __restrict__ out)
{
    __shared__ float red[256];
    __shared__ float part[64];
    __shared__ float irs0s;
    // rs0 total (redundant per block; 80KB L2-resident)
    float sv = 0.f;
    for (int i = threadIdx.x; i < NN; i += 256) sv += rs0part[i];
    red[threadIdx.x] = sv;
    __syncthreads();
    for (int off = 128; off > 0; off >>= 1) {
        if (threadIdx.x < off) red[threadIdx.x] += red[threadIdx.x + off];
        __syncthreads();
    }
    if (threadIdx.x == 0) irs0s = 1.0f / fmaxf(red[0], 1e-6f);
    __syncthreads();
    float irs0 = irs0s;
    // Abuf0 partial rows
    int lane = threadIdx.x & 63, w = threadIdx.x >> 6;
    float sum = 0.f;
    for (int ss = blockIdx.x + 64 * w; ss < NN; ss += 256)
        sum += Abuf0[(size_t)ss * EMB + lane];
    red[threadIdx.x] = sum;
    __syncthreads();
    if (threadIdx.x < 64) {
        part[threadIdx.x] = red[threadIdx.x] + red[threadIdx.x + 64] +
                            red[threadIdx.x + 128] + red[threadIdx.x + 192];
    }
    __syncthreads();
    if (threadIdx.x < 64) {
        int hq = threadIdx.x >> 4, c = threadIdx.x & 15;
        float v = 0.f;
#pragma unroll
        for (int hh = 0; hh < 16; ++hh) {
            int hd = hq * 16 + hh;
            v = fmaf(part[hd], w2[hd * NCLS + c], v);
        }
        v += __shfl_xor(v, 16, 64);
        v += __shfl_xor(v, 32, 64);
        if (threadIdx.x < 16) atomicAdd(&out[c], v * irs0);
    }
}

extern "C" void kernel_launch(void* const* d_in, const int* in_sizes, int n_in,
                              void* d_out, int out_size, void* d_ws, size_t ws_size,
                              hipStream_t stream)
{
    const float* rm    = (const float*)d_in[0];
    const int*   hrow  = (const int*)d_in[1];   // sorted source nodes
    const int*   vcol  = (const int*)d_in[4];   // object nodes
    const float* W1    = (const float*)d_in[5];
    const float* b1    = (const float*)d_in[6];
    const float* W2    = (const float*)d_in[7];
    const float* b2    = (const float*)d_in[8];
    const float* w1    = (const float*)d_in[9];
    const float* w2    = (const float*)d_in[10];
    const float* bias1 = (const float*)d_in[11];
    const float* bias2 = (const float*)d_in[12];
    float* out = (float*)d_out;

    float* ws = (float*)d_ws;
    float*  l1      = ws;                       // [0, 2.00M)
    float*  l2      = ws + 2000000;             // [2.00M, 4.00M)
    int*    rowptr  = (int*)(ws + 4000000);     // 20,001 ints
    float*  colsum  = ws + 4100000;             // 160,000 (raw; divided in k_contrib)
    float*  rowsum  = ws + 4260000;             // 140,000 (raw; divided in k_l2out)  [contiguous w/ colsum]
    __half* h       = (__half*)(ws + 4400000);  // 1.28M halfs [4.40M, 5.04M)
    int*    cnt     = (int*)(ws + 5040000);     // 20,000
    int*    cstart  = cnt + 20000;              // 20,001
    int*    cnt2    = cstart + 20001;           // 20,000
    int*    cscidx  = cnt2 + 20000;             // 250,000 (ends 5.35M)
    __half* contrib = (__half*)(ws + 5600000);  // 16M halfs [5.60M, 13.60M)
    // Abuf0/rs0part overlay l1 (l1 dead after k_contrib)
    float*  Abuf0   = ws;                       // 1.28M
    float*  rs0part = ws + 1280000;             // 20,000

    hipMemsetAsync(colsum, 0, (size_t)300000 * sizeof(float), stream);   // colsum + rowsum (contiguous)
    hipMemsetAsync(cnt, 0, (size_t)20000 * sizeof(int), stream);

    k_gemv   <<<GEMVB + RPB + HIB + OIB, 256, 0, stream>>>(rm, W1, b1, W2, b2, l1, l2,
                                                           hrow, rowptr, vcol, cnt, out, bias2);
    k_scan   <<<1, 1024, 0, stream>>>(cnt, cstart, cnt2);
    k_pos    <<<(NT + 255) / 256, 256, 0, stream>>>(vcol, cnt2, cscidx);
    k_colsum <<<NN / 4 + REDB, 256, 0, stream>>>(l1, cstart, cscidx, colsum);
    k_contrib<<<(NN * 64) / 256, 256, 0, stream>>>(l1, colsum, cstart, cscidx, w1, contrib);
    k_h      <<<(NN * 64) / 256, 256, 0, stream>>>(contrib, l2, rowptr, bias1, h, rowsum, rs0part);
    k_l2out  <<<(NN * 64) / 256, 256, 0, stream>>>(l2, rowptr, vcol, h, rowsum, w2, out, Abuf0);
    k_redA   <<<64, 256, 0, stream>>>(Abuf0, rs0part, w2, out);
}